// Round 9
// baseline (318.024 us; speedup 1.0000x reference)
//
#include <hip/hip_runtime.h>
#include <hip/hip_bf16.h>
#include <stdint.h>
#include <stddef.h>

typedef __hip_bfloat16 bf16;
typedef short bf16x8 __attribute__((ext_vector_type(8)));
typedef float f32x4 __attribute__((ext_vector_type(4)));

// Problem constants
#define BB 2
#define SS 2048
#define DM 2048
#define NH 32
#define NG 8
#define DH 64
#define ROWS (BB * SS)   // 4096
#define NQK 2560         // Q cols (2048) + K cols (512)

// sqrt(0.125 * log2(e)) — applied to BOTH Q and K columns in the QK-proj GEMM,
// so S = (aQ)(aK)^T arrives pre-scaled for exp2-domain softmax.
#define ALPHA_QK 0.4246609001440095f

__device__ __forceinline__ void gload_lds16(const void* g, void* l) {
  __builtin_amdgcn_global_load_lds((const __attribute__((address_space(1))) void*)g,
                                   (__attribute__((address_space(3))) void*)l, 16, 0, 0);
}

__device__ __forceinline__ unsigned cvt_pk_bf16(float lo, float hi) {
  unsigned r;
  asm("v_cvt_pk_bf16_f32 %0, %1, %2" : "=v"(r) : "v"(lo), "v"(hi));
  return r;
}

// ---------------- fused f32 -> bf16 convert for all 5 inputs ----------------
__global__ __launch_bounds__(256) void cvt_all(const float* __restrict__ x,
                                               const float* __restrict__ wq,
                                               const float* __restrict__ wk,
                                               const float* __restrict__ wv,
                                               const float* __restrict__ wo,
                                               bf16* __restrict__ xb,
                                               bf16* __restrict__ wqkb,
                                               bf16* __restrict__ wvb,
                                               bf16* __restrict__ wob) {
  const int i = blockIdx.x * 256 + threadIdx.x;
  const float* src;
  bf16* dst;
  if (i < 2097152)       { src = x  + (size_t)i * 4;              dst = xb   + (size_t)i * 4; }
  else if (i < 3145728)  { size_t j = i - 2097152; src = wq + j * 4; dst = wqkb + j * 4; }
  else if (i < 3407872)  { size_t j = i - 3145728; src = wk + j * 4; dst = wqkb + 4194304 + j * 4; }
  else if (i < 3670016)  { size_t j = i - 3407872; src = wv + j * 4; dst = wvb  + j * 4; }
  else                   { size_t j = i - 3670016; src = wo + j * 4; dst = wob  + j * 4; }
  float4 v = *reinterpret_cast<const float4*>(src);
  bf16 t0 = __float2bfloat16(v.x), t1 = __float2bfloat16(v.y);
  bf16 t2 = __float2bfloat16(v.z), t3 = __float2bfloat16(v.w);
  ushort4 o;
  o.x = *reinterpret_cast<unsigned short*>(&t0);
  o.y = *reinterpret_cast<unsigned short*>(&t1);
  o.z = *reinterpret_cast<unsigned short*>(&t2);
  o.w = *reinterpret_cast<unsigned short*>(&t3);
  *reinterpret_cast<ushort4*>(dst) = o;
}

// ---------------- GEMM: C[M][N] = alpha * A[M][K] * B[N][K]^T ----
// 3-deep circular global_load_lds pipeline with COUNTED vmcnt (T4) +
// T1 XCD-contiguous swizzle (all launches have nwg % 8 == 0).
__device__ __forceinline__ void store_elem(float* C, size_t i, float v) { C[i] = v; }
__device__ __forceinline__ void store_elem(bf16* C, size_t i, float v) { C[i] = __float2bfloat16(v); }

template <typename CT>
__global__ __launch_bounds__(256) void gemm_bt(const bf16* __restrict__ A,
                                               const bf16* __restrict__ Bm,
                                               CT* __restrict__ C,
                                               int M, int N, int K, float alpha) {
  const int t = threadIdx.x;
  const int w = t >> 6, lane = t & 63, lg = lane >> 4, lr = lane & 15;
  const int wr = w >> 1, wc = w & 1;
  const int nwg = gridDim.x * gridDim.y;
  const int flat = blockIdx.y * gridDim.x + blockIdx.x;
  const int swz = (flat & 7) * (nwg >> 3) + (flat >> 3);
  const int rowA = (swz / gridDim.x) * 128, rowB = (swz % gridDim.x) * 128;
  __shared__ __align__(16) bf16 sA[3][128 * 32];
  __shared__ __align__(16) bf16 sB[3][128 * 32];
  f32x4 acc[4][4] = {};

  auto STAGE = [&](int bi, int k0) {               // 4 gload_lds / lane
#pragma unroll
    for (int i = 0; i < 2; ++i) {
      const int c = i * 256 + t;           // 16B chunk index, 4 chunks/row
      const int r = c >> 2, slot = c & 3;
      const int ck = slot ^ ((r >> 1) & 3);
      gload_lds16(A + (size_t)(rowA + r) * K + k0 + ck * 8, &sA[bi][c * 8]);
      gload_lds16(Bm + (size_t)(rowB + r) * K + k0 + ck * 8, &sB[bi][c * 8]);
    }
  };

  const int nt = K / 32;
  STAGE(0, 0);
  STAGE(1, 32);
  STAGE(2, 64);

  for (int i = 0; i < nt; ++i) {
    if (i <= nt - 3)      asm volatile("s_waitcnt vmcnt(8)" ::: "memory");
    else if (i == nt - 2) asm volatile("s_waitcnt vmcnt(4)" ::: "memory");
    else                  asm volatile("s_waitcnt vmcnt(0)" ::: "memory");
    __builtin_amdgcn_s_barrier();

    const int bi = i % 3;
    bf16x8 af[4], bfv[4];
#pragma unroll
    for (int mi = 0; mi < 4; ++mi) {
      const int r = wr * 64 + mi * 16 + lr;
      af[mi] = *(const bf16x8*)&sA[bi][r * 32 + (lg ^ ((r >> 1) & 3)) * 8];
    }
#pragma unroll
    for (int ni = 0; ni < 4; ++ni) {
      const int r = wc * 64 + ni * 16 + lr;
      bfv[ni] = *(const bf16x8*)&sB[bi][r * 32 + (lg ^ ((r >> 1) & 3)) * 8];
    }
    asm volatile("s_waitcnt lgkmcnt(0)" ::: "memory");
    __builtin_amdgcn_sched_barrier(0);
    __builtin_amdgcn_s_barrier();
    if (i + 3 < nt) STAGE(bi, (i + 3) * 32);
#pragma unroll
    for (int mi = 0; mi < 4; ++mi)
#pragma unroll
      for (int ni = 0; ni < 4; ++ni)
        acc[mi][ni] = __builtin_amdgcn_mfma_f32_16x16x32_bf16(af[mi], bfv[ni], acc[mi][ni], 0, 0, 0);
  }

#pragma unroll
  for (int mi = 0; mi < 4; ++mi)
#pragma unroll
    for (int ni = 0; ni < 4; ++ni) {
      const int row0 = rowA + wr * 64 + mi * 16 + 4 * lg;
      const int col = rowB + wc * 64 + ni * 16 + lr;
#pragma unroll
      for (int r = 0; r < 4; ++r)
        store_elem(C, (size_t)(row0 + r) * N + col, acc[mi][ni][r] * alpha);
    }
}

// ---------------- fused GQA flash attention (swapped QK^T, V-direct) --------
// qk: [4096][2560] bf16, PRE-SCALED by sqrt(0.125*log2e) on both Q and K parts.
// vt: [512][4096] bf16 (row = g*64+d, col = b*2048+s)
// ctx: [4096][2048] bf16 out
// Block = 128 q-rows (4 waves x 32 rows), KV tile = 64.
// V is read DIRECT from global as MFMA B-fragments (L2-resident via XCD remap,
// verified by r8's FETCH_SIZE drop). K double-buffered in LDS with round-4's
// PROVEN single-__syncthreads STAGE-at-top structure. LDS 34.4 KB.
__global__ __launch_bounds__(256, 3) void gqa_attn(const bf16* __restrict__ qk,
                                                   const bf16* __restrict__ vt,
                                                   bf16* __restrict__ ctx) {
  const int t = threadIdx.x, w = t >> 6, lane = t & 63, lg = lane >> 4, lr = lane & 15;
  // bijective remap: flat = xcd + 8*idx  ->  wg = xcd*128 + idx
  const int flat = blockIdx.x;
  const int wg = (flat & 7) * 128 + (flat >> 3);
  const int head = wg >> 4;                 // 0..63
  const int qb = (wg & 15) * 128;           // 16 q-blocks of 128 rows
  const int b = head >> 5, h = head & 31, g = h >> 2;
  const size_t LD = NQK;
  const bf16* Qp = qk + (size_t)b * SS * LD + h * 64;
  const bf16* Kp = qk + (size_t)b * SS * LD + 2048 + g * 64;
  const bf16* Vt = vt + (size_t)(g * 64) * ROWS + b * SS;

  __shared__ __align__(16) bf16 sK[2][64 * 64];      // [key][d], slot-swizzled, dbuf
  __shared__ __align__(16) bf16 sP[4][32 * 72];      // per-wave P (32 q-rows), stride 72

  // Q B-fragments (Q^T as B-operand): lane holds q=lr, d = 8*lg+j.
  bf16x8 qf[2][2];
#pragma unroll
  for (int mi = 0; mi < 2; ++mi) {
    const bf16* qrow = Qp + (size_t)(qb + w * 32 + mi * 16 + lr) * LD;
    qf[mi][0] = *(const bf16x8*)(qrow + lg * 8);
    qf[mi][1] = *(const bf16x8*)(qrow + 32 + lg * 8);
  }

  float m_run[2], l_part[2];                          // per-lane: q = lr (per mi)
  f32x4 o[2][4];
#pragma unroll
  for (int mi = 0; mi < 2; ++mi) {
    m_run[mi] = -3.0e38f;
    l_part[mi] = 0.0f;
#pragma unroll
    for (int dg = 0; dg < 4; ++dg) o[mi][dg] = (f32x4){0.f, 0.f, 0.f, 0.f};
  }

  auto STAGE = [&](int bi, int kt) {                 // 2 gload_lds / lane (K only)
#pragma unroll
    for (int i = 0; i < 2; ++i) {
      const int c = i * 256 + t;           // 16B chunk, 8 chunks/row, 512 total
      const int r = c >> 3, slot = c & 7;
      const int ck = slot ^ (r & 7);
      gload_lds16(Kp + (size_t)(kt * 64 + r) * LD + ck * 8, &sK[bi][c * 8]);
    }
  };

  const int NT = SS / 64;
  STAGE(0, 0);
  __syncthreads();                          // full drain: tile 0 resident
  int cur = 0;

  for (int kt = 0; kt < NT; ++kt) {
    // round-4-proven pattern: issue next tile's staging first, compute, syncthreads
    if (kt + 1 < NT) STAGE(cur ^ 1, kt + 1);

    // V fragments direct from global (L2-resident slab); issued early so the
    // L2 latency hides under QK^T + softmax. Element-identical to the old sV path.
    bf16x8 vfr[2][4];
#pragma unroll
    for (int kc = 0; kc < 2; ++kc)
#pragma unroll
      for (int dg = 0; dg < 4; ++dg)
        vfr[kc][dg] = *(const bf16x8*)(Vt + (size_t)(dg * 16 + lr) * ROWS +
                                       kt * 64 + kc * 32 + lg * 8);

    // S^T = K Q^T  (s[mi][cg][r] = S[q = lr][k = cg*16 + 4*lg + r])
    f32x4 s[2][4];
    __builtin_amdgcn_s_setprio(1);
#pragma unroll
    for (int cg = 0; cg < 4; ++cg) {
      const int kr = cg * 16 + lr;
      bf16x8 kf0 = *(const bf16x8*)&sK[cur][kr * 64 + ((lg) ^ (kr & 7)) * 8];
      bf16x8 kf1 = *(const bf16x8*)&sK[cur][kr * 64 + ((lg + 4) ^ (kr & 7)) * 8];
#pragma unroll
      for (int mi = 0; mi < 2; ++mi) {
        f32x4 z = {0.f, 0.f, 0.f, 0.f};
        z = __builtin_amdgcn_mfma_f32_16x16x32_bf16(kf0, qf[mi][0], z, 0, 0, 0);
        z = __builtin_amdgcn_mfma_f32_16x16x32_bf16(kf1, qf[mi][1], z, 0, 0, 0);
        s[mi][cg] = z;
      }
    }
    __builtin_amdgcn_s_setprio(0);

    // T13 defer-max: lane-local max over this lane's 16 k-values (its q-row slice)
    float pm[2];
    bool ok = true;
#pragma unroll
    for (int mi = 0; mi < 2; ++mi) {
      float m0 = fmaxf(fmaxf(s[mi][0][0], s[mi][0][1]), fmaxf(s[mi][0][2], s[mi][0][3]));
      float m1 = fmaxf(fmaxf(s[mi][1][0], s[mi][1][1]), fmaxf(s[mi][1][2], s[mi][1][3]));
      float m2 = fmaxf(fmaxf(s[mi][2][0], s[mi][2][1]), fmaxf(s[mi][2][2], s[mi][2][3]));
      float m3 = fmaxf(fmaxf(s[mi][3][0], s[mi][3][1]), fmaxf(s[mi][3][2], s[mi][3][3]));
      pm[mi] = fmaxf(fmaxf(m0, m1), fmaxf(m2, m3));
      ok = ok && (pm[mi] <= m_run[mi] + 8.f);
    }
    if (!__all(ok)) {
#pragma unroll
      for (int mi = 0; mi < 2; ++mi) {
        float m = pm[mi];
        m = fmaxf(m, __shfl_xor(m, 16));   // reduce across the 4 lg-groups
        m = fmaxf(m, __shfl_xor(m, 32));
        const float mn = fmaxf(m_run[mi], m);
        const float corr = __builtin_amdgcn_exp2f(m_run[mi] - mn);
        m_run[mi] = mn;
        l_part[mi] *= corr;
#pragma unroll
        for (int r = 0; r < 4; ++r) {
          const float co = __shfl(corr, 20 * lg + r);
#pragma unroll
          for (int dg = 0; dg < 4; ++dg) o[mi][dg][r] *= co;
        }
      }
    }

    // P = exp2(s - m): lane-local q-row; pack pairs (k-consecutive) -> b64 writes
    bf16* sPw = sP[w];
#pragma unroll
    for (int mi = 0; mi < 2; ++mi) {
#pragma unroll
      for (int cg = 0; cg < 4; ++cg) {
        float p0 = __builtin_amdgcn_exp2f(s[mi][cg][0] - m_run[mi]);
        float p1 = __builtin_amdgcn_exp2f(s[mi][cg][1] - m_run[mi]);
        float p2 = __builtin_amdgcn_exp2f(s[mi][cg][2] - m_run[mi]);
        float p3 = __builtin_amdgcn_exp2f(s[mi][cg][3] - m_run[mi]);
        l_part[mi] += (p0 + p1) + (p2 + p3);
        uint2 pk;
        pk.x = cvt_pk_bf16(p0, p1);
        pk.y = cvt_pk_bf16(p2, p3);
        *(uint2*)&sPw[(mi * 16 + lr) * 72 + cg * 16 + 4 * lg] = pk;
      }
    }

    // O += P @ V  (A = P [16 q][64 k], B = V frags from global)
#pragma unroll
    for (int kc = 0; kc < 2; ++kc) {
      bf16x8 pf[2];
#pragma unroll
      for (int mi = 0; mi < 2; ++mi)
        pf[mi] = *(const bf16x8*)&sPw[(mi * 16 + lr) * 72 + kc * 32 + lg * 8];
      __builtin_amdgcn_s_setprio(1);
#pragma unroll
      for (int dg = 0; dg < 4; ++dg)
#pragma unroll
        for (int mi = 0; mi < 2; ++mi)
          o[mi][dg] = __builtin_amdgcn_mfma_f32_16x16x32_bf16(pf[mi], vfr[kc][dg], o[mi][dg], 0, 0, 0);
      __builtin_amdgcn_s_setprio(0);
    }

    __syncthreads();    // full drain + barrier: next K tile resident, buf cur free
    cur ^= 1;
  }

  // final l: sum across lg-groups (q = lr), then hop to O layout (q = 4*lg + r)
#pragma unroll
  for (int mi = 0; mi < 2; ++mi) {
    float l = l_part[mi];
    l += __shfl_xor(l, 16);
    l += __shfl_xor(l, 32);
    const int orow0 = b * SS + qb + w * 32 + mi * 16 + 4 * lg;
#pragma unroll
    for (int r = 0; r < 4; ++r) {
      const float lo = __shfl(l, 20 * lg + r);
      const float inv = 1.0f / lo;
      const int row = orow0 + r;
#pragma unroll
      for (int dg = 0; dg < 4; ++dg) {
        const int col = h * 64 + dg * 16 + lr;
        ctx[(size_t)row * DM + col] = __float2bfloat16(o[mi][dg][r] * inv);
      }
    }
  }
}

// ---------------- launch ----------------
extern "C" void kernel_launch(void* const* d_in, const int* in_sizes, int n_in,
                              void* d_out, int out_size, void* d_ws, size_t ws_size,
                              hipStream_t stream) {
  const float* x   = (const float*)d_in[0];
  const float* W_q = (const float*)d_in[1];
  const float* W_k = (const float*)d_in[2];
  const float* W_v = (const float*)d_in[3];
  const float* W_o = (const float*)d_in[4];
  float* out = (float*)d_out;

  char* ws = (char*)d_ws;
  bf16* xb    = (bf16*)ws; ws += (size_t)ROWS * DM * 2;
  bf16* wqk   = (bf16*)ws; ws += (size_t)NQK * DM * 2;
  bf16* wv    = (bf16*)ws; ws += (size_t)(NG * DH) * DM * 2;
  bf16* wo    = (bf16*)ws; ws += (size_t)DM * DM * 2;
  bf16* qkbuf = (bf16*)ws; ws += (size_t)ROWS * NQK * 2;
  bf16* vtb   = (bf16*)ws; ws += (size_t)(NG * DH) * ROWS * 2;
  bf16* ctx   = (bf16*)ws; ws += (size_t)ROWS * DM * 2;

  // one fused convert: 4,718,592 float4 chunks / 256 = 18432 blocks
  cvt_all<<<18432, 256, 0, stream>>>(x, W_q, W_k, W_v, W_o, xb, wqk, wv, wo);

  // QK projection with exp2-softmax scale folded into BOTH Q and K columns
  gemm_bt<bf16><<<dim3(NQK / 128, ROWS / 128), 256, 0, stream>>>(xb, wqk, qkbuf, ROWS, NQK, DM, ALPHA_QK);
  // V projection, transposed: vtb[512][4096] = wv @ xb^T
  gemm_bt<bf16><<<dim3(ROWS / 128, (NG * DH) / 128), 256, 0, stream>>>(wv, xb, vtb, NG * DH, ROWS, DM, 1.0f);
  // attention: 1024 blocks, XCD-remapped inside the kernel
  gqa_attn<<<1024, 256, 0, stream>>>(qkbuf, vtb, ctx);
  // output projection: out[4096][2048] f32 = ctx @ wo^T
  gemm_bt<float><<<dim3(DM / 128, ROWS / 128), 256, 0, stream>>>(ctx, wo, out, ROWS, DM, DM, 1.0f);
}

// Round 11
// 220.261 us; speedup vs baseline: 1.4439x; 1.4439x over previous
//
#include <hip/hip_runtime.h>
#include <hip/hip_bf16.h>
#include <stdint.h>
#include <stddef.h>

typedef __hip_bfloat16 bf16;
typedef short bf16x8 __attribute__((ext_vector_type(8)));
typedef float f32x4 __attribute__((ext_vector_type(4)));

// Problem constants
#define BB 2
#define SS 2048
#define DM 2048
#define NH 32
#define NG 8
#define DH 64
#define ROWS (BB * SS)   // 4096
#define NQK 2560         // Q cols (2048) + K cols (512)

// sqrt(0.125 * log2(e)) — applied to BOTH Q and K columns in the QK-proj GEMM,
// so S = (aQ)(aK)^T arrives pre-scaled for exp2-domain softmax.
#define ALPHA_QK 0.4246609001440095f

__device__ __forceinline__ void gload_lds16(const void* g, void* l) {
  __builtin_amdgcn_global_load_lds((const __attribute__((address_space(1))) void*)g,
                                   (__attribute__((address_space(3))) void*)l, 16, 0, 0);
}

__device__ __forceinline__ unsigned cvt_pk_bf16(float lo, float hi) {
  unsigned r;
  asm("v_cvt_pk_bf16_f32 %0, %1, %2" : "=v"(r) : "v"(lo), "v"(hi));
  return r;
}

__device__ __forceinline__ float max3f(float a, float b, float c) {
  float r;
  asm("v_max3_f32 %0, %1, %2, %3" : "=v"(r) : "v"(a), "v"(b), "v"(c));
  return r;
}

// ---------------- fused f32 -> bf16 convert for all 5 inputs ----------------
__global__ __launch_bounds__(256) void cvt_all(const float* __restrict__ x,
                                               const float* __restrict__ wq,
                                               const float* __restrict__ wk,
                                               const float* __restrict__ wv,
                                               const float* __restrict__ wo,
                                               bf16* __restrict__ xb,
                                               bf16* __restrict__ wqkb,
                                               bf16* __restrict__ wvb,
                                               bf16* __restrict__ wob) {
  const int i = blockIdx.x * 256 + threadIdx.x;
  const float* src;
  bf16* dst;
  if (i < 2097152)       { src = x  + (size_t)i * 4;              dst = xb   + (size_t)i * 4; }
  else if (i < 3145728)  { size_t j = i - 2097152; src = wq + j * 4; dst = wqkb + j * 4; }
  else if (i < 3407872)  { size_t j = i - 3145728; src = wk + j * 4; dst = wqkb + 4194304 + j * 4; }
  else if (i < 3670016)  { size_t j = i - 3407872; src = wv + j * 4; dst = wvb  + j * 4; }
  else                   { size_t j = i - 3670016; src = wo + j * 4; dst = wob  + j * 4; }
  float4 v = *reinterpret_cast<const float4*>(src);
  bf16 t0 = __float2bfloat16(v.x), t1 = __float2bfloat16(v.y);
  bf16 t2 = __float2bfloat16(v.z), t3 = __float2bfloat16(v.w);
  ushort4 o;
  o.x = *reinterpret_cast<unsigned short*>(&t0);
  o.y = *reinterpret_cast<unsigned short*>(&t1);
  o.z = *reinterpret_cast<unsigned short*>(&t2);
  o.w = *reinterpret_cast<unsigned short*>(&t3);
  *reinterpret_cast<ushort4*>(dst) = o;
}

// ---------------- GEMM core: C[M][N] = alpha * A * B^T, 128^2 tile ----------
// 3-deep circular global_load_lds pipeline with COUNTED vmcnt (T4).
__device__ __forceinline__ void store_elem(float* C, size_t i, float v) { C[i] = v; }
__device__ __forceinline__ void store_elem(bf16* C, size_t i, float v) { C[i] = __float2bfloat16(v); }

template <typename CT>
__device__ __forceinline__ void gemm_body(const bf16* __restrict__ A,
                                          const bf16* __restrict__ Bm,
                                          CT* __restrict__ C,
                                          int rowA, int rowB, int N, int K, float alpha,
                                          bf16 (*sA)[128 * 32], bf16 (*sB)[128 * 32]) {
  const int t = threadIdx.x;
  const int w = t >> 6, lane = t & 63, lg = lane >> 4, lr = lane & 15;
  const int wr = w >> 1, wc = w & 1;
  f32x4 acc[4][4] = {};

  auto STAGE = [&](int bi, int k0) {               // 4 gload_lds / lane
#pragma unroll
    for (int i = 0; i < 2; ++i) {
      const int c = i * 256 + t;           // 16B chunk index, 4 chunks/row
      const int r = c >> 2, slot = c & 3;
      const int ck = slot ^ ((r >> 1) & 3);
      gload_lds16(A + (size_t)(rowA + r) * K + k0 + ck * 8, &sA[bi][c * 8]);
      gload_lds16(Bm + (size_t)(rowB + r) * K + k0 + ck * 8, &sB[bi][c * 8]);
    }
  };

  const int nt = K / 32;
  STAGE(0, 0);
  STAGE(1, 32);
  STAGE(2, 64);

  for (int i = 0; i < nt; ++i) {
    if (i <= nt - 3)      asm volatile("s_waitcnt vmcnt(8)" ::: "memory");
    else if (i == nt - 2) asm volatile("s_waitcnt vmcnt(4)" ::: "memory");
    else                  asm volatile("s_waitcnt vmcnt(0)" ::: "memory");
    __builtin_amdgcn_s_barrier();

    const int bi = i % 3;
    bf16x8 af[4], bfv[4];
#pragma unroll
    for (int mi = 0; mi < 4; ++mi) {
      const int r = wr * 64 + mi * 16 + lr;
      af[mi] = *(const bf16x8*)&sA[bi][r * 32 + (lg ^ ((r >> 1) & 3)) * 8];
    }
#pragma unroll
    for (int ni = 0; ni < 4; ++ni) {
      const int r = wc * 64 + ni * 16 + lr;
      bfv[ni] = *(const bf16x8*)&sB[bi][r * 32 + (lg ^ ((r >> 1) & 3)) * 8];
    }
    asm volatile("s_waitcnt lgkmcnt(0)" ::: "memory");
    __builtin_amdgcn_sched_barrier(0);
    __builtin_amdgcn_s_barrier();
    if (i + 3 < nt) STAGE(bi, (i + 3) * 32);
#pragma unroll
    for (int mi = 0; mi < 4; ++mi)
#pragma unroll
      for (int ni = 0; ni < 4; ++ni)
        acc[mi][ni] = __builtin_amdgcn_mfma_f32_16x16x32_bf16(af[mi], bfv[ni], acc[mi][ni], 0, 0, 0);
  }

#pragma unroll
  for (int mi = 0; mi < 4; ++mi)
#pragma unroll
    for (int ni = 0; ni < 4; ++ni) {
      const int row0 = rowA + wr * 64 + mi * 16 + 4 * lg;
      const int col = rowB + wc * 64 + ni * 16 + lr;
#pragma unroll
      for (int r = 0; r < 4; ++r)
        store_elem(C, (size_t)(row0 + r) * N + col, acc[mi][ni][r] * alpha);
    }
}

// Merged QK-proj + V-proj: 768 blocks (640 QK + 128 V), one XCD swizzle domain.
__global__ __launch_bounds__(256) void gemm_qkv(const bf16* __restrict__ xb,
                                                const bf16* __restrict__ wqk,
                                                const bf16* __restrict__ wv,
                                                bf16* __restrict__ qkbuf,
                                                bf16* __restrict__ vtb) {
  __shared__ __align__(16) bf16 sA[3][128 * 32];
  __shared__ __align__(16) bf16 sB[3][128 * 32];
  const int flat = blockIdx.x;                     // 768 total, %8==0
  const int swz = (flat & 7) * 96 + (flat >> 3);   // XCD-contiguous, bijective
  if (swz < 640) {
    // QK projection: qkbuf[4096][2560] = alpha * xb @ wqk^T  (grid 32x20)
    const int rowA = (swz / 20) * 128, rowB = (swz % 20) * 128;
    gemm_body<bf16>(xb, wqk, qkbuf, rowA, rowB, NQK, DM, ALPHA_QK, sA, sB);
  } else {
    // V projection (transposed out): vtb[512][4096] = wv @ xb^T  (grid 4x32)
    const int j = swz - 640;
    const int rowA = (j / 32) * 128, rowB = (j % 32) * 128;
    gemm_body<bf16>(wv, xb, vtb, rowA, rowB, ROWS, DM, 1.0f, sA, sB);
  }
}

// O-projection: out[4096][2048] f32 = ctx @ wo^T (512 blocks)
__global__ __launch_bounds__(256) void gemm_out(const bf16* __restrict__ ctx,
                                                const bf16* __restrict__ wo,
                                                float* __restrict__ out) {
  __shared__ __align__(16) bf16 sA[3][128 * 32];
  __shared__ __align__(16) bf16 sB[3][128 * 32];
  const int nwg = gridDim.x;                       // 512
  const int flat = blockIdx.x;
  const int swz = (flat & 7) * (nwg >> 3) + (flat >> 3);
  const int rowA = (swz / 16) * 128, rowB = (swz % 16) * 128;
  gemm_body<float>(ctx, wo, out, rowA, rowB, DM, DM, 1.0f, sA, sB);
}

// ---------------- fused GQA flash attention (r8-PROVEN body, scalar l) ------
// qk: [4096][2560] bf16, PRE-SCALED by sqrt(0.125*log2e) on both Q and K parts.
// vt: [512][4096] bf16 (row = g*64+d, col = b*2048+s)
// ctx: [4096][2048] bf16 out
// Block = 128 q-rows (4 waves x 32 rows), KV tile = 64, 2-deep counted-vmcnt dbuf.
// NOTE: ones-MFMA l-accumulation is PERMANENTLY SHELVED — failed 2/2 on HW in
// this swapped-QK structure (r7: 2512, r10: 5536) while scalar l passed 3/3.
__global__ __launch_bounds__(256, 3) void gqa_attn(const bf16* __restrict__ qk,
                                                   const bf16* __restrict__ vt,
                                                   bf16* __restrict__ ctx) {
  const int t = threadIdx.x, w = t >> 6, lane = t & 63, lg = lane >> 4, lr = lane & 15;
  // bijective remap: flat = xcd + 8*idx  ->  wg = xcd*128 + idx
  const int flat = blockIdx.x;
  const int wg = (flat & 7) * 128 + (flat >> 3);
  const int head = wg >> 4;                 // 0..63
  const int qb = (wg & 15) * 128;           // 16 q-blocks of 128 rows
  const int b = head >> 5, h = head & 31, g = h >> 2;
  const size_t LD = NQK;
  const bf16* Qp = qk + (size_t)b * SS * LD + h * 64;
  const bf16* Kp = qk + (size_t)b * SS * LD + 2048 + g * 64;
  const bf16* Vt = vt + (size_t)(g * 64) * ROWS + b * SS;

  __shared__ __align__(16) bf16 sK[2][64 * 64];      // [key][d], slot-swizzled, dbuf
  __shared__ __align__(16) bf16 sV[2][64 * 64];      // [d][key], slot-swizzled, dbuf
  __shared__ __align__(16) bf16 sP[4][32 * 72];      // per-wave P (32 q-rows), stride 72

  // Q B-fragments (Q^T as B-operand): lane holds q=lr, d = 8*lg+j.
  bf16x8 qf[2][2];
#pragma unroll
  for (int mi = 0; mi < 2; ++mi) {
    const bf16* qrow = Qp + (size_t)(qb + w * 32 + mi * 16 + lr) * LD;
    qf[mi][0] = *(const bf16x8*)(qrow + lg * 8);
    qf[mi][1] = *(const bf16x8*)(qrow + 32 + lg * 8);
  }
  asm volatile("s_waitcnt vmcnt(0)" ::: "memory");   // deterministic vmcnt counting

  float m_run[2], l_part[2];                          // per-lane: q = lr (per mi)
  f32x4 o[2][4];
#pragma unroll
  for (int mi = 0; mi < 2; ++mi) {
    m_run[mi] = -3.0e38f;
    l_part[mi] = 0.0f;
#pragma unroll
    for (int dg = 0; dg < 4; ++dg) o[mi][dg] = (f32x4){0.f, 0.f, 0.f, 0.f};
  }

  auto STAGE = [&](int bi, int kt) {                 // 4 gload_lds / lane
#pragma unroll
    for (int i = 0; i < 2; ++i) {
      const int c = i * 256 + t;           // 16B chunk, 8 chunks/row
      const int r = c >> 3, slot = c & 7;
      const int ck = slot ^ (r & 7);
      gload_lds16(Kp + (size_t)(kt * 64 + r) * LD + ck * 8, &sK[bi][c * 8]);
      gload_lds16(Vt + (size_t)r * ROWS + kt * 64 + ck * 8, &sV[bi][c * 8]);
    }
  };

  const int NT = SS / 64;
  STAGE(0, 0);
  int cur = 0;

  for (int kt = 0; kt < NT; ++kt) {
    if (kt + 1 < NT) {
      STAGE(cur ^ 1, kt + 1);
      asm volatile("s_waitcnt vmcnt(4)" ::: "memory");
    } else {
      asm volatile("s_waitcnt vmcnt(0)" ::: "memory");
    }
    __builtin_amdgcn_s_barrier();

    // S^T = K Q^T  (s[mi][cg][r] = S[q = lr][k = cg*16 + 4*lg + r])
    f32x4 s[2][4];
    __builtin_amdgcn_s_setprio(1);
#pragma unroll
    for (int cg = 0; cg < 4; ++cg) {
      const int kr = cg * 16 + lr;
      bf16x8 kf0 = *(const bf16x8*)&sK[cur][kr * 64 + ((lg) ^ (kr & 7)) * 8];
      bf16x8 kf1 = *(const bf16x8*)&sK[cur][kr * 64 + ((lg + 4) ^ (kr & 7)) * 8];
#pragma unroll
      for (int mi = 0; mi < 2; ++mi) {
        f32x4 z = {0.f, 0.f, 0.f, 0.f};
        z = __builtin_amdgcn_mfma_f32_16x16x32_bf16(kf0, qf[mi][0], z, 0, 0, 0);
        z = __builtin_amdgcn_mfma_f32_16x16x32_bf16(kf1, qf[mi][1], z, 0, 0, 0);
        s[mi][cg] = z;
      }
    }
    __builtin_amdgcn_s_setprio(0);

    // T13 defer-max + T17 max3: lane-local max over this lane's 16 k-values.
    // (max3 is ratio-neutral: online softmax is exact for any shared m_run.)
    float pm[2];
    bool ok = true;
#pragma unroll
    for (int mi = 0; mi < 2; ++mi) {
      float a0 = max3f(s[mi][0][0], s[mi][0][1], s[mi][0][2]);
      float a1 = max3f(s[mi][0][3], s[mi][1][0], s[mi][1][1]);
      float a2 = max3f(s[mi][1][2], s[mi][1][3], s[mi][2][0]);
      float a3 = max3f(s[mi][2][1], s[mi][2][2], s[mi][2][3]);
      float a4 = max3f(s[mi][3][0], s[mi][3][1], s[mi][3][2]);
      pm[mi] = fmaxf(max3f(a0, a1, a2), max3f(a3, a4, s[mi][3][3]));
      ok = ok && (pm[mi] <= m_run[mi] + 8.f);
    }
    if (!__all(ok)) {
#pragma unroll
      for (int mi = 0; mi < 2; ++mi) {
        float m = pm[mi];
        m = fmaxf(m, __shfl_xor(m, 16));   // reduce across the 4 lg-groups
        m = fmaxf(m, __shfl_xor(m, 32));
        const float mn = fmaxf(m_run[mi], m);
        const float corr = __builtin_amdgcn_exp2f(m_run[mi] - mn);
        m_run[mi] = mn;
        l_part[mi] *= corr;
        // O rows live at q_local = 4*lg + r — fetch corr from the lane owning that q
#pragma unroll
        for (int r = 0; r < 4; ++r) {
          const float co = __shfl(corr, 20 * lg + r);
#pragma unroll
          for (int dg = 0; dg < 4; ++dg) o[mi][dg][r] *= co;
        }
      }
    }

    // P = exp2(s - m): lane-local q-row; pack pairs (k-consecutive) -> b64 writes
    bf16* sPw = sP[w];
#pragma unroll
    for (int mi = 0; mi < 2; ++mi) {
#pragma unroll
      for (int cg = 0; cg < 4; ++cg) {
        float p0 = __builtin_amdgcn_exp2f(s[mi][cg][0] - m_run[mi]);
        float p1 = __builtin_amdgcn_exp2f(s[mi][cg][1] - m_run[mi]);
        float p2 = __builtin_amdgcn_exp2f(s[mi][cg][2] - m_run[mi]);
        float p3 = __builtin_amdgcn_exp2f(s[mi][cg][3] - m_run[mi]);
        l_part[mi] += (p0 + p1) + (p2 + p3);
        uint2 pk;
        pk.x = cvt_pk_bf16(p0, p1);
        pk.y = cvt_pk_bf16(p2, p3);
        *(uint2*)&sPw[(mi * 16 + lr) * 72 + cg * 16 + 4 * lg] = pk;
      }
    }

    // O += P @ V  (A = P [16 q][64 k], B = V [64 k][16 d])
#pragma unroll
    for (int kc = 0; kc < 2; ++kc) {
      bf16x8 pf[2];
#pragma unroll
      for (int mi = 0; mi < 2; ++mi)
        pf[mi] = *(const bf16x8*)&sPw[(mi * 16 + lr) * 72 + kc * 32 + lg * 8];
      __builtin_amdgcn_s_setprio(1);
#pragma unroll
      for (int dg = 0; dg < 4; ++dg) {
        const int vr = dg * 16 + lr;
        bf16x8 vf = *(const bf16x8*)&sV[cur][vr * 64 + ((kc * 4 + lg) ^ (vr & 7)) * 8];
#pragma unroll
        for (int mi = 0; mi < 2; ++mi)
          o[mi][dg] = __builtin_amdgcn_mfma_f32_16x16x32_bf16(pf[mi], vf, o[mi][dg], 0, 0, 0);
      }
      __builtin_amdgcn_s_setprio(0);
    }

    asm volatile("s_waitcnt lgkmcnt(0)" ::: "memory");
    __builtin_amdgcn_sched_barrier(0);
    __builtin_amdgcn_s_barrier();
    cur ^= 1;
  }

  // final l: sum across lg-groups (q = lr), then hop to O layout (q = 4*lg + r)
#pragma unroll
  for (int mi = 0; mi < 2; ++mi) {
    float l = l_part[mi];
    l += __shfl_xor(l, 16);
    l += __shfl_xor(l, 32);
    const int orow0 = b * SS + qb + w * 32 + mi * 16 + 4 * lg;
#pragma unroll
    for (int r = 0; r < 4; ++r) {
      const float lo = __shfl(l, 20 * lg + r);
      const float inv = 1.0f / lo;
      const int row = orow0 + r;
#pragma unroll
      for (int dg = 0; dg < 4; ++dg) {
        const int col = h * 64 + dg * 16 + lr;
        ctx[(size_t)row * DM + col] = __float2bfloat16(o[mi][dg][r] * inv);
      }
    }
  }
}

// ---------------- launch ----------------
extern "C" void kernel_launch(void* const* d_in, const int* in_sizes, int n_in,
                              void* d_out, int out_size, void* d_ws, size_t ws_size,
                              hipStream_t stream) {
  const float* x   = (const float*)d_in[0];
  const float* W_q = (const float*)d_in[1];
  const float* W_k = (const float*)d_in[2];
  const float* W_v = (const float*)d_in[3];
  const float* W_o = (const float*)d_in[4];
  float* out = (float*)d_out;

  char* ws = (char*)d_ws;
  bf16* xb    = (bf16*)ws; ws += (size_t)ROWS * DM * 2;
  bf16* wqk   = (bf16*)ws; ws += (size_t)NQK * DM * 2;
  bf16* wv    = (bf16*)ws; ws += (size_t)(NG * DH) * DM * 2;
  bf16* wo    = (bf16*)ws; ws += (size_t)DM * DM * 2;
  bf16* qkbuf = (bf16*)ws; ws += (size_t)ROWS * NQK * 2;
  bf16* vtb   = (bf16*)ws; ws += (size_t)(NG * DH) * ROWS * 2;
  bf16* ctx   = (bf16*)ws; ws += (size_t)ROWS * DM * 2;

  // one fused convert: 4,718,592 float4 chunks / 256 = 18432 blocks
  cvt_all<<<18432, 256, 0, stream>>>(x, W_q, W_k, W_v, W_o, xb, wqk, wv, wo);

  // merged QK-proj (exp2 scale folded) + V-proj(transposed): 768 blocks
  gemm_qkv<<<768, 256, 0, stream>>>(xb, wqk, wv, qkbuf, vtb);
  // attention: 1024 blocks, XCD-remapped inside the kernel
  gqa_attn<<<1024, 256, 0, stream>>>(qkbuf, vtb, ctx);
  // output projection: out[4096][2048] f32 = ctx @ wo^T
  gemm_out<<<512, 256, 0, stream>>>(ctx, wo, out);
}

// Round 12
// 212.286 us; speedup vs baseline: 1.4981x; 1.0376x over previous
//
#include <hip/hip_runtime.h>
#include <hip/hip_bf16.h>
#include <stdint.h>
#include <stddef.h>

typedef __hip_bfloat16 bf16;
typedef short bf16x8 __attribute__((ext_vector_type(8)));
typedef float f32x4 __attribute__((ext_vector_type(4)));

// Problem constants
#define BB 2
#define SS 2048
#define DM 2048
#define NH 32
#define NG 8
#define DH 64
#define ROWS (BB * SS)   // 4096
#define NQK 2560         // Q cols (2048) + K cols (512)

// sqrt(0.125 * log2(e)) — applied to BOTH Q and K columns in the QK-proj GEMM,
// so S = (aQ)(aK)^T arrives pre-scaled for exp2-domain softmax.
#define ALPHA_QK 0.4246609001440095f

__device__ __forceinline__ void gload_lds16(const void* g, void* l) {
  __builtin_amdgcn_global_load_lds((const __attribute__((address_space(1))) void*)g,
                                   (__attribute__((address_space(3))) void*)l, 16, 0, 0);
}

__device__ __forceinline__ unsigned cvt_pk_bf16(float lo, float hi) {
  unsigned r;
  asm("v_cvt_pk_bf16_f32 %0, %1, %2" : "=v"(r) : "v"(lo), "v"(hi));
  return r;
}

__device__ __forceinline__ float max3f(float a, float b, float c) {
  float r;
  asm("v_max3_f32 %0, %1, %2, %3" : "=v"(r) : "v"(a), "v"(b), "v"(c));
  return r;
}

union U8 { uint4 u; bf16x8 v; };

// ---------------- fused f32 -> bf16 convert for all 5 inputs ----------------
__global__ __launch_bounds__(256) void cvt_all(const float* __restrict__ x,
                                               const float* __restrict__ wq,
                                               const float* __restrict__ wk,
                                               const float* __restrict__ wv,
                                               const float* __restrict__ wo,
                                               bf16* __restrict__ xb,
                                               bf16* __restrict__ wqkb,
                                               bf16* __restrict__ wvb,
                                               bf16* __restrict__ wob) {
  const int i = blockIdx.x * 256 + threadIdx.x;
  const float* src;
  bf16* dst;
  if (i < 2097152)       { src = x  + (size_t)i * 4;              dst = xb   + (size_t)i * 4; }
  else if (i < 3145728)  { size_t j = i - 2097152; src = wq + j * 4; dst = wqkb + j * 4; }
  else if (i < 3407872)  { size_t j = i - 3145728; src = wk + j * 4; dst = wqkb + 4194304 + j * 4; }
  else if (i < 3670016)  { size_t j = i - 3407872; src = wv + j * 4; dst = wvb  + j * 4; }
  else                   { size_t j = i - 3670016; src = wo + j * 4; dst = wob  + j * 4; }
  float4 v = *reinterpret_cast<const float4*>(src);
  bf16 t0 = __float2bfloat16(v.x), t1 = __float2bfloat16(v.y);
  bf16 t2 = __float2bfloat16(v.z), t3 = __float2bfloat16(v.w);
  ushort4 o;
  o.x = *reinterpret_cast<unsigned short*>(&t0);
  o.y = *reinterpret_cast<unsigned short*>(&t1);
  o.z = *reinterpret_cast<unsigned short*>(&t2);
  o.w = *reinterpret_cast<unsigned short*>(&t3);
  *reinterpret_cast<ushort4*>(dst) = o;
}

// ---------------- GEMM core: C[M][N] = alpha * A * B^T, 128^2 tile ----------
// 3-deep circular global_load_lds pipeline with COUNTED vmcnt (T4).
__device__ __forceinline__ void store_elem(float* C, size_t i, float v) { C[i] = v; }
__device__ __forceinline__ void store_elem(bf16* C, size_t i, float v) { C[i] = __float2bfloat16(v); }

template <typename CT>
__device__ __forceinline__ void gemm_body(const bf16* __restrict__ A,
                                          const bf16* __restrict__ Bm,
                                          CT* __restrict__ C,
                                          int rowA, int rowB, int N, int K, float alpha,
                                          bf16 (*sA)[128 * 32], bf16 (*sB)[128 * 32]) {
  const int t = threadIdx.x;
  const int w = t >> 6, lane = t & 63, lg = lane >> 4, lr = lane & 15;
  const int wr = w >> 1, wc = w & 1;
  f32x4 acc[4][4] = {};

  auto STAGE = [&](int bi, int k0) {               // 4 gload_lds / lane
#pragma unroll
    for (int i = 0; i < 2; ++i) {
      const int c = i * 256 + t;           // 16B chunk index, 4 chunks/row
      const int r = c >> 2, slot = c & 3;
      const int ck = slot ^ ((r >> 1) & 3);
      gload_lds16(A + (size_t)(rowA + r) * K + k0 + ck * 8, &sA[bi][c * 8]);
      gload_lds16(Bm + (size_t)(rowB + r) * K + k0 + ck * 8, &sB[bi][c * 8]);
    }
  };

  const int nt = K / 32;
  STAGE(0, 0);
  STAGE(1, 32);
  STAGE(2, 64);

  for (int i = 0; i < nt; ++i) {
    if (i <= nt - 3)      asm volatile("s_waitcnt vmcnt(8)" ::: "memory");
    else if (i == nt - 2) asm volatile("s_waitcnt vmcnt(4)" ::: "memory");
    else                  asm volatile("s_waitcnt vmcnt(0)" ::: "memory");
    __builtin_amdgcn_s_barrier();

    const int bi = i % 3;
    bf16x8 af[4], bfv[4];
#pragma unroll
    for (int mi = 0; mi < 4; ++mi) {
      const int r = wr * 64 + mi * 16 + lr;
      af[mi] = *(const bf16x8*)&sA[bi][r * 32 + (lg ^ ((r >> 1) & 3)) * 8];
    }
#pragma unroll
    for (int ni = 0; ni < 4; ++ni) {
      const int r = wc * 64 + ni * 16 + lr;
      bfv[ni] = *(const bf16x8*)&sB[bi][r * 32 + (lg ^ ((r >> 1) & 3)) * 8];
    }
    asm volatile("s_waitcnt lgkmcnt(0)" ::: "memory");
    __builtin_amdgcn_sched_barrier(0);
    __builtin_amdgcn_s_barrier();
    if (i + 3 < nt) STAGE(bi, (i + 3) * 32);
#pragma unroll
    for (int mi = 0; mi < 4; ++mi)
#pragma unroll
      for (int ni = 0; ni < 4; ++ni)
        acc[mi][ni] = __builtin_amdgcn_mfma_f32_16x16x32_bf16(af[mi], bfv[ni], acc[mi][ni], 0, 0, 0);
  }

#pragma unroll
  for (int mi = 0; mi < 4; ++mi)
#pragma unroll
    for (int ni = 0; ni < 4; ++ni) {
      const int row0 = rowA + wr * 64 + mi * 16 + 4 * lg;
      const int col = rowB + wc * 64 + ni * 16 + lr;
#pragma unroll
      for (int r = 0; r < 4; ++r)
        store_elem(C, (size_t)(row0 + r) * N + col, acc[mi][ni][r] * alpha);
    }
}

// Merged QK-proj + V-proj: 768 blocks (640 QK + 128 V), one XCD swizzle domain.
__global__ __launch_bounds__(256) void gemm_qkv(const bf16* __restrict__ xb,
                                                const bf16* __restrict__ wqk,
                                                const bf16* __restrict__ wv,
                                                bf16* __restrict__ qkbuf,
                                                bf16* __restrict__ vtb) {
  __shared__ __align__(16) bf16 sA[3][128 * 32];
  __shared__ __align__(16) bf16 sB[3][128 * 32];
  const int flat = blockIdx.x;                     // 768 total, %8==0
  const int swz = (flat & 7) * 96 + (flat >> 3);   // XCD-contiguous, bijective
  if (swz < 640) {
    const int rowA = (swz / 20) * 128, rowB = (swz % 20) * 128;
    gemm_body<bf16>(xb, wqk, qkbuf, rowA, rowB, NQK, DM, ALPHA_QK, sA, sB);
  } else {
    const int j = swz - 640;
    const int rowA = (j / 32) * 128, rowB = (j % 32) * 128;
    gemm_body<bf16>(wv, xb, vtb, rowA, rowB, ROWS, DM, 1.0f, sA, sB);
  }
}

// O-projection: out[4096][2048] f32 = ctx @ wo^T (512 blocks)
__global__ __launch_bounds__(256) void gemm_out(const bf16* __restrict__ ctx,
                                                const bf16* __restrict__ wo,
                                                float* __restrict__ out) {
  __shared__ __align__(16) bf16 sA[3][128 * 32];
  __shared__ __align__(16) bf16 sB[3][128 * 32];
  const int nwg = gridDim.x;                       // 512
  const int flat = blockIdx.x;
  const int swz = (flat & 7) * (nwg >> 3) + (flat >> 3);
  const int rowA = (swz / 16) * 128, rowB = (swz % 16) * 128;
  gemm_body<float>(ctx, wo, out, rowA, rowB, DM, DM, 1.0f, sA, sB);
}

// ---------------- fused GQA flash attention (reg-resident P) -----------------
// qk: [4096][2560] bf16, PRE-SCALED by sqrt(0.125*log2e) on both Q and K parts.
// vt: [512][4096] bf16 (row = g*64+d, col = b*2048+s)
// ctx: [4096][2048] bf16 out
// Block = 128 q-rows (4 waves x 32 rows), KV tile = 64, 2-deep counted-vmcnt dbuf.
// P stays in registers: MFMA k-slots are relabeled by the bijection
// f(lg,j) = 32kc + 16*(j>=4) + 4lg + (j&3), applied identically to the P
// A-fragment (pure register repack of the cvt_pk outputs) and the V B-fragment
// (two ds_read_b64 at matching swizzled chunks). No sP, LDS 32.8 KB.
// ones-MFMA l remains SHELVED (failed 2/2 on HW); scalar l_part proven 4/4.
__global__ __launch_bounds__(256, 4) void gqa_attn(const bf16* __restrict__ qk,
                                                   const bf16* __restrict__ vt,
                                                   bf16* __restrict__ ctx) {
  const int t = threadIdx.x, w = t >> 6, lane = t & 63, lg = lane >> 4, lr = lane & 15;
  // bijective remap: flat = xcd + 8*idx  ->  wg = xcd*128 + idx
  const int flat = blockIdx.x;
  const int wg = (flat & 7) * 128 + (flat >> 3);
  const int head = wg >> 4;                 // 0..63
  const int qb = (wg & 15) * 128;           // 16 q-blocks of 128 rows
  const int b = head >> 5, h = head & 31, g = h >> 2;
  const size_t LD = NQK;
  const bf16* Qp = qk + (size_t)b * SS * LD + h * 64;
  const bf16* Kp = qk + (size_t)b * SS * LD + 2048 + g * 64;
  const bf16* Vt = vt + (size_t)(g * 64) * ROWS + b * SS;

  __shared__ __align__(16) bf16 sK[2][64 * 64];      // [key][d], slot-swizzled, dbuf
  __shared__ __align__(16) bf16 sV[2][64 * 64];      // [d][key], slot-swizzled, dbuf

  // Q B-fragments (Q^T as B-operand): lane holds q=lr, d = 8*lg+j.
  bf16x8 qf[2][2];
#pragma unroll
  for (int mi = 0; mi < 2; ++mi) {
    const bf16* qrow = Qp + (size_t)(qb + w * 32 + mi * 16 + lr) * LD;
    qf[mi][0] = *(const bf16x8*)(qrow + lg * 8);
    qf[mi][1] = *(const bf16x8*)(qrow + 32 + lg * 8);
  }
  asm volatile("s_waitcnt vmcnt(0)" ::: "memory");   // deterministic vmcnt counting

  float m_run[2], l_part[2];                          // per-lane: q = lr (per mi)
  f32x4 o[2][4];
#pragma unroll
  for (int mi = 0; mi < 2; ++mi) {
    m_run[mi] = -3.0e38f;
    l_part[mi] = 0.0f;
#pragma unroll
    for (int dg = 0; dg < 4; ++dg) o[mi][dg] = (f32x4){0.f, 0.f, 0.f, 0.f};
  }

  auto STAGE = [&](int bi, int kt) {                 // 4 gload_lds / lane
#pragma unroll
    for (int i = 0; i < 2; ++i) {
      const int c = i * 256 + t;           // 16B chunk, 8 chunks/row
      const int r = c >> 3, slot = c & 7;
      const int ck = slot ^ (r & 7);
      gload_lds16(Kp + (size_t)(kt * 64 + r) * LD + ck * 8, &sK[bi][c * 8]);
      gload_lds16(Vt + (size_t)r * ROWS + kt * 64 + ck * 8, &sV[bi][c * 8]);
    }
  };

  const int NT = SS / 64;
  STAGE(0, 0);
  int cur = 0;

  for (int kt = 0; kt < NT; ++kt) {
    if (kt + 1 < NT) {
      STAGE(cur ^ 1, kt + 1);
      asm volatile("s_waitcnt vmcnt(4)" ::: "memory");
    } else {
      asm volatile("s_waitcnt vmcnt(0)" ::: "memory");
    }
    __builtin_amdgcn_s_barrier();

    // S^T = K Q^T  (s[mi][cg][r] = S[q = lr][k = cg*16 + 4*lg + r])
    f32x4 s[2][4];
    __builtin_amdgcn_s_setprio(1);
#pragma unroll
    for (int cg = 0; cg < 4; ++cg) {
      const int kr = cg * 16 + lr;
      bf16x8 kf0 = *(const bf16x8*)&sK[cur][kr * 64 + ((lg) ^ (kr & 7)) * 8];
      bf16x8 kf1 = *(const bf16x8*)&sK[cur][kr * 64 + ((lg + 4) ^ (kr & 7)) * 8];
#pragma unroll
      for (int mi = 0; mi < 2; ++mi) {
        f32x4 z = {0.f, 0.f, 0.f, 0.f};
        z = __builtin_amdgcn_mfma_f32_16x16x32_bf16(kf0, qf[mi][0], z, 0, 0, 0);
        z = __builtin_amdgcn_mfma_f32_16x16x32_bf16(kf1, qf[mi][1], z, 0, 0, 0);
        s[mi][cg] = z;
      }
    }
    __builtin_amdgcn_s_setprio(0);

    // T13 defer-max + T17 max3: lane-local max over this lane's 16 k-values.
    float pm[2];
    bool ok = true;
#pragma unroll
    for (int mi = 0; mi < 2; ++mi) {
      float a0 = max3f(s[mi][0][0], s[mi][0][1], s[mi][0][2]);
      float a1 = max3f(s[mi][0][3], s[mi][1][0], s[mi][1][1]);
      float a2 = max3f(s[mi][1][2], s[mi][1][3], s[mi][2][0]);
      float a3 = max3f(s[mi][2][1], s[mi][2][2], s[mi][2][3]);
      float a4 = max3f(s[mi][3][0], s[mi][3][1], s[mi][3][2]);
      pm[mi] = fmaxf(max3f(a0, a1, a2), max3f(a3, a4, s[mi][3][3]));
      ok = ok && (pm[mi] <= m_run[mi] + 8.f);
    }
    if (!__all(ok)) {
#pragma unroll
      for (int mi = 0; mi < 2; ++mi) {
        float m = pm[mi];
        m = fmaxf(m, __shfl_xor(m, 16));   // reduce across the 4 lg-groups
        m = fmaxf(m, __shfl_xor(m, 32));
        const float mn = fmaxf(m_run[mi], m);
        const float corr = __builtin_amdgcn_exp2f(m_run[mi] - mn);
        m_run[mi] = mn;
        l_part[mi] *= corr;
        // O rows live at q_local = 4*lg + r — fetch corr from the lane owning that q
#pragma unroll
        for (int r = 0; r < 4; ++r) {
          const float co = __shfl(corr, 20 * lg + r);
#pragma unroll
          for (int dg = 0; dg < 4; ++dg) o[mi][dg][r] *= co;
        }
      }
    }

    // P = exp2(s - m): lane-local q-row; pack to bf16 pairs IN REGISTERS.
    // pk[mi][cg] holds k = 16cg + 4lg + {0,1} (x) and {2,3} (y).
    uint2 pk[2][4];
#pragma unroll
    for (int mi = 0; mi < 2; ++mi) {
#pragma unroll
      for (int cg = 0; cg < 4; ++cg) {
        float p0 = __builtin_amdgcn_exp2f(s[mi][cg][0] - m_run[mi]);
        float p1 = __builtin_amdgcn_exp2f(s[mi][cg][1] - m_run[mi]);
        float p2 = __builtin_amdgcn_exp2f(s[mi][cg][2] - m_run[mi]);
        float p3 = __builtin_amdgcn_exp2f(s[mi][cg][3] - m_run[mi]);
        l_part[mi] += (p0 + p1) + (p2 + p3);
        pk[mi][cg].x = cvt_pk_bf16(p0, p1);
        pk[mi][cg].y = cvt_pk_bf16(p2, p3);
      }
    }

    // O += P @ V under the k-slot bijection f(lg,j)=32kc+16*(j>=4)+4lg+(j&3).
    // A-frag: pure register repack. B-frag: two b64 reads at matching chunks.
#pragma unroll
    for (int kc = 0; kc < 2; ++kc) {
      bf16x8 pf[2];
#pragma unroll
      for (int mi = 0; mi < 2; ++mi) {
        U8 a;
        a.u.x = pk[mi][2 * kc].x;      // j=0,1 : k = 32kc + 4lg + {0,1}
        a.u.y = pk[mi][2 * kc].y;      // j=2,3 : k = 32kc + 4lg + {2,3}
        a.u.z = pk[mi][2 * kc + 1].x;  // j=4,5 : k = 32kc + 16 + 4lg + {0,1}
        a.u.w = pk[mi][2 * kc + 1].y;  // j=6,7 : k = 32kc + 16 + 4lg + {2,3}
        pf[mi] = a.v;
      }
      __builtin_amdgcn_s_setprio(1);
#pragma unroll
      for (int dg = 0; dg < 4; ++dg) {
        const int vr = dg * 16 + lr;
        // global k-chunks 4kc+2s+(lg>>1) (s=0,1), at swizzled slot ^(vr&7),
        // within-chunk element offset 4*(lg&1)
        const int c0 = (((4 * kc + (lg >> 1)) ^ (vr & 7)) << 3) + ((lg & 1) << 2);
        const int c1 = (((4 * kc + 2 + (lg >> 1)) ^ (vr & 7)) << 3) + ((lg & 1) << 2);
        uint2 lo = *(const uint2*)&sV[cur][vr * 64 + c0];
        uint2 hi = *(const uint2*)&sV[cur][vr * 64 + c1];
        U8 vv;
        vv.u.x = lo.x; vv.u.y = lo.y; vv.u.z = hi.x; vv.u.w = hi.y;
#pragma unroll
        for (int mi = 0; mi < 2; ++mi)
          o[mi][dg] = __builtin_amdgcn_mfma_f32_16x16x32_bf16(pf[mi], vv.v, o[mi][dg], 0, 0, 0);
      }
      __builtin_amdgcn_s_setprio(0);
    }

    asm volatile("s_waitcnt lgkmcnt(0)" ::: "memory");
    __builtin_amdgcn_sched_barrier(0);
    __builtin_amdgcn_s_barrier();
    cur ^= 1;
  }

  // final l: sum across lg-groups (q = lr), then hop to O layout (q = 4*lg + r)
#pragma unroll
  for (int mi = 0; mi < 2; ++mi) {
    float l = l_part[mi];
    l += __shfl_xor(l, 16);
    l += __shfl_xor(l, 32);
    const int orow0 = b * SS + qb + w * 32 + mi * 16 + 4 * lg;
#pragma unroll
    for (int r = 0; r < 4; ++r) {
      const float lo = __shfl(l, 20 * lg + r);
      const float inv = 1.0f / lo;
      const int row = orow0 + r;
#pragma unroll
      for (int dg = 0; dg < 4; ++dg) {
        const int col = h * 64 + dg * 16 + lr;
        ctx[(size_t)row * DM + col] = __float2bfloat16(o[mi][dg][r] * inv);
      }
    }
  }
}

// ---------------- launch ----------------
extern "C" void kernel_launch(void* const* d_in, const int* in_sizes, int n_in,
                              void* d_out, int out_size, void* d_ws, size_t ws_size,
                              hipStream_t stream) {
  const float* x   = (const float*)d_in[0];
  const float* W_q = (const float*)d_in[1];
  const float* W_k = (const float*)d_in[2];
  const float* W_v = (const float*)d_in[3];
  const float* W_o = (const float*)d_in[4];
  float* out = (float*)d_out;

  char* ws = (char*)d_ws;
  bf16* xb    = (bf16*)ws; ws += (size_t)ROWS * DM * 2;
  bf16* wqk   = (bf16*)ws; ws += (size_t)NQK * DM * 2;
  bf16* wv    = (bf16*)ws; ws += (size_t)(NG * DH) * DM * 2;
  bf16* wo    = (bf16*)ws; ws += (size_t)DM * DM * 2;
  bf16* qkbuf = (bf16*)ws; ws += (size_t)ROWS * NQK * 2;
  bf16* vtb   = (bf16*)ws; ws += (size_t)(NG * DH) * ROWS * 2;
  bf16* ctx   = (bf16*)ws; ws += (size_t)ROWS * DM * 2;

  // one fused convert: 4,718,592 float4 chunks / 256 = 18432 blocks
  cvt_all<<<18432, 256, 0, stream>>>(x, W_q, W_k, W_v, W_o, xb, wqk, wv, wo);

  // merged QK-proj (exp2 scale folded) + V-proj(transposed): 768 blocks
  gemm_qkv<<<768, 256, 0, stream>>>(xb, wqk, wv, qkbuf, vtb);
  // attention: 1024 blocks, XCD-remapped inside the kernel
  gqa_attn<<<1024, 256, 0, stream>>>(qkbuf, vtb, ctx);
  // output projection: out[4096][2048] f32 = ctx @ wo^T
  gemm_out<<<512, 256, 0, stream>>>(ctx, wo, out);
}

// Round 13
// 208.446 us; speedup vs baseline: 1.5257x; 1.0184x over previous
//
#include <hip/hip_runtime.h>
#include <hip/hip_bf16.h>
#include <stdint.h>
#include <stddef.h>

typedef __hip_bfloat16 bf16;
typedef short bf16x8 __attribute__((ext_vector_type(8)));
typedef float f32x4 __attribute__((ext_vector_type(4)));

// Problem constants
#define BB 2
#define SS 2048
#define DM 2048
#define NH 32
#define NG 8
#define DH 64
#define ROWS (BB * SS)   // 4096
#define NQK 2560         // Q cols (2048) + K cols (512)

// sqrt(0.125 * log2(e)) — applied to BOTH Q and K columns in the QK-proj GEMM,
// so S = (aQ)(aK)^T arrives pre-scaled for exp2-domain softmax.
#define ALPHA_QK 0.4246609001440095f

__device__ __forceinline__ void gload_lds16(const void* g, void* l) {
  __builtin_amdgcn_global_load_lds((const __attribute__((address_space(1))) void*)g,
                                   (__attribute__((address_space(3))) void*)l, 16, 0, 0);
}

__device__ __forceinline__ unsigned cvt_pk_bf16(float lo, float hi) {
  unsigned r;
  asm("v_cvt_pk_bf16_f32 %0, %1, %2" : "=v"(r) : "v"(lo), "v"(hi));
  return r;
}

__device__ __forceinline__ float max3f(float a, float b, float c) {
  float r;
  asm("v_max3_f32 %0, %1, %2, %3" : "=v"(r) : "v"(a), "v"(b), "v"(c));
  return r;
}

union U8 { uint4 u; bf16x8 v; };

// ---------------- fused f32 -> bf16 convert for all 5 inputs ----------------
__global__ __launch_bounds__(256) void cvt_all(const float* __restrict__ x,
                                               const float* __restrict__ wq,
                                               const float* __restrict__ wk,
                                               const float* __restrict__ wv,
                                               const float* __restrict__ wo,
                                               bf16* __restrict__ xb,
                                               bf16* __restrict__ wqkb,
                                               bf16* __restrict__ wvb,
                                               bf16* __restrict__ wob) {
  const int i = blockIdx.x * 256 + threadIdx.x;
  const float* src;
  bf16* dst;
  if (i < 2097152)       { src = x  + (size_t)i * 4;              dst = xb   + (size_t)i * 4; }
  else if (i < 3145728)  { size_t j = i - 2097152; src = wq + j * 4; dst = wqkb + j * 4; }
  else if (i < 3407872)  { size_t j = i - 3145728; src = wk + j * 4; dst = wqkb + 4194304 + j * 4; }
  else if (i < 3670016)  { size_t j = i - 3407872; src = wv + j * 4; dst = wvb  + j * 4; }
  else                   { size_t j = i - 3670016; src = wo + j * 4; dst = wob  + j * 4; }
  float4 v = *reinterpret_cast<const float4*>(src);
  bf16 t0 = __float2bfloat16(v.x), t1 = __float2bfloat16(v.y);
  bf16 t2 = __float2bfloat16(v.z), t3 = __float2bfloat16(v.w);
  ushort4 o;
  o.x = *reinterpret_cast<unsigned short*>(&t0);
  o.y = *reinterpret_cast<unsigned short*>(&t1);
  o.z = *reinterpret_cast<unsigned short*>(&t2);
  o.w = *reinterpret_cast<unsigned short*>(&t3);
  *reinterpret_cast<ushort4*>(dst) = o;
}

// ---------------- GEMM core: C[M][N] = alpha * A * B^T, 128^2 tile ----------
// 3-deep circular global_load_lds pipeline with COUNTED vmcnt (T4).
// LDS fragment offsets are tile-invariant -> hoisted before the K-loop.
__device__ __forceinline__ void store_elem(float* C, size_t i, float v) { C[i] = v; }
__device__ __forceinline__ void store_elem(bf16* C, size_t i, float v) { C[i] = __float2bfloat16(v); }

template <typename CT>
__device__ __forceinline__ void gemm_body(const bf16* __restrict__ A,
                                          const bf16* __restrict__ Bm,
                                          CT* __restrict__ C,
                                          int rowA, int rowB, int N, int K, float alpha,
                                          bf16 (*sA)[128 * 32], bf16 (*sB)[128 * 32]) {
  const int t = threadIdx.x;
  const int w = t >> 6, lane = t & 63, lg = lane >> 4, lr = lane & 15;
  const int wr = w >> 1, wc = w & 1;
  f32x4 acc[4][4] = {};

  // hoisted tile-invariant LDS element offsets
  int aOff[4], bOff[4];
#pragma unroll
  for (int mi = 0; mi < 4; ++mi) {
    const int r = wr * 64 + mi * 16 + lr;
    aOff[mi] = r * 32 + (lg ^ ((r >> 1) & 3)) * 8;
  }
#pragma unroll
  for (int ni = 0; ni < 4; ++ni) {
    const int r = wc * 64 + ni * 16 + lr;
    bOff[ni] = r * 32 + (lg ^ ((r >> 1) & 3)) * 8;
  }

  auto STAGE = [&](int bi, int k0) {               // 4 gload_lds / lane
#pragma unroll
    for (int i = 0; i < 2; ++i) {
      const int c = i * 256 + t;           // 16B chunk index, 4 chunks/row
      const int r = c >> 2, slot = c & 3;
      const int ck = slot ^ ((r >> 1) & 3);
      gload_lds16(A + (size_t)(rowA + r) * K + k0 + ck * 8, &sA[bi][c * 8]);
      gload_lds16(Bm + (size_t)(rowB + r) * K + k0 + ck * 8, &sB[bi][c * 8]);
    }
  };

  const int nt = K / 32;
  STAGE(0, 0);
  STAGE(1, 32);
  STAGE(2, 64);

  for (int i = 0; i < nt; ++i) {
    if (i <= nt - 3)      asm volatile("s_waitcnt vmcnt(8)" ::: "memory");
    else if (i == nt - 2) asm volatile("s_waitcnt vmcnt(4)" ::: "memory");
    else                  asm volatile("s_waitcnt vmcnt(0)" ::: "memory");
    __builtin_amdgcn_s_barrier();

    const int bi = i % 3;
    const bf16* Ab = sA[bi];
    const bf16* Bb = sB[bi];
    bf16x8 af[4], bfv[4];
#pragma unroll
    for (int mi = 0; mi < 4; ++mi) af[mi] = *(const bf16x8*)&Ab[aOff[mi]];
#pragma unroll
    for (int ni = 0; ni < 4; ++ni) bfv[ni] = *(const bf16x8*)&Bb[bOff[ni]];
    asm volatile("s_waitcnt lgkmcnt(0)" ::: "memory");
    __builtin_amdgcn_sched_barrier(0);
    __builtin_amdgcn_s_barrier();
    if (i + 3 < nt) STAGE(bi, (i + 3) * 32);
#pragma unroll
    for (int mi = 0; mi < 4; ++mi)
#pragma unroll
      for (int ni = 0; ni < 4; ++ni)
        acc[mi][ni] = __builtin_amdgcn_mfma_f32_16x16x32_bf16(af[mi], bfv[ni], acc[mi][ni], 0, 0, 0);
  }

#pragma unroll
  for (int mi = 0; mi < 4; ++mi)
#pragma unroll
    for (int ni = 0; ni < 4; ++ni) {
      const int row0 = rowA + wr * 64 + mi * 16 + 4 * lg;
      const int col = rowB + wc * 64 + ni * 16 + lr;
#pragma unroll
      for (int r = 0; r < 4; ++r)
        store_elem(C, (size_t)(row0 + r) * N + col, acc[mi][ni][r] * alpha);
    }
}

// Merged QK-proj + V-proj: 768 blocks (640 QK + 128 V), one XCD swizzle domain.
__global__ __launch_bounds__(256) void gemm_qkv(const bf16* __restrict__ xb,
                                                const bf16* __restrict__ wqk,
                                                const bf16* __restrict__ wv,
                                                bf16* __restrict__ qkbuf,
                                                bf16* __restrict__ vtb) {
  __shared__ __align__(16) bf16 sA[3][128 * 32];
  __shared__ __align__(16) bf16 sB[3][128 * 32];
  const int flat = blockIdx.x;                     // 768 total, %8==0
  const int swz = (flat & 7) * 96 + (flat >> 3);   // XCD-contiguous, bijective
  if (swz < 640) {
    const int rowA = (swz / 20) * 128, rowB = (swz % 20) * 128;
    gemm_body<bf16>(xb, wqk, qkbuf, rowA, rowB, NQK, DM, ALPHA_QK, sA, sB);
  } else {
    const int j = swz - 640;
    const int rowA = (j / 32) * 128, rowB = (j % 32) * 128;
    gemm_body<bf16>(wv, xb, vtb, rowA, rowB, ROWS, DM, 1.0f, sA, sB);
  }
}

// O-projection: out[4096][2048] f32 = ctx @ wo^T (512 blocks)
__global__ __launch_bounds__(256) void gemm_out(const bf16* __restrict__ ctx,
                                                const bf16* __restrict__ wo,
                                                float* __restrict__ out) {
  __shared__ __align__(16) bf16 sA[3][128 * 32];
  __shared__ __align__(16) bf16 sB[3][128 * 32];
  const int nwg = gridDim.x;                       // 512
  const int flat = blockIdx.x;
  const int swz = (flat & 7) * (nwg >> 3) + (flat >> 3);
  const int rowA = (swz / 16) * 128, rowB = (swz % 16) * 128;
  gemm_body<float>(ctx, wo, out, rowA, rowB, DM, DM, 1.0f, sA, sB);
}

// ---------------- fused GQA flash attention (reg-resident P, hoisted addrs) --
// qk: [4096][2560] bf16, PRE-SCALED by sqrt(0.125*log2e) on both Q and K parts.
// vt: [512][4096] bf16 (row = g*64+d, col = b*2048+s)
// ctx: [4096][2048] bf16 out
// Block = 128 q-rows (4 waves x 32 rows), KV tile = 64, 2-deep counted-vmcnt dbuf.
// P stays in registers via the k-slot bijection f(lg,j)=32kc+16*(j>=4)+4lg+(j&3)
// (A-frag = register repack; V B-frag = two ds_read_b64 at matching chunks).
// All LDS read offsets are tile-invariant -> hoisted before the KV loop.
// ones-MFMA l remains SHELVED (failed 2/2 on HW); scalar l_part proven 4/4.
__global__ __launch_bounds__(256, 4) void gqa_attn(const bf16* __restrict__ qk,
                                                   const bf16* __restrict__ vt,
                                                   bf16* __restrict__ ctx) {
  const int t = threadIdx.x, w = t >> 6, lane = t & 63, lg = lane >> 4, lr = lane & 15;
  // bijective remap: flat = xcd + 8*idx  ->  wg = xcd*128 + idx
  const int flat = blockIdx.x;
  const int wg = (flat & 7) * 128 + (flat >> 3);
  const int head = wg >> 4;                 // 0..63
  const int qb = (wg & 15) * 128;           // 16 q-blocks of 128 rows
  const int b = head >> 5, h = head & 31, g = h >> 2;
  const size_t LD = NQK;
  const bf16* Qp = qk + (size_t)b * SS * LD + h * 64;
  const bf16* Kp = qk + (size_t)b * SS * LD + 2048 + g * 64;
  const bf16* Vt = vt + (size_t)(g * 64) * ROWS + b * SS;

  __shared__ __align__(16) bf16 sK[2][64 * 64];      // [key][d], slot-swizzled, dbuf
  __shared__ __align__(16) bf16 sV[2][64 * 64];      // [d][key], slot-swizzled, dbuf

  // Q B-fragments (Q^T as B-operand): lane holds q=lr, d = 8*lg+j.
  bf16x8 qf[2][2];
#pragma unroll
  for (int mi = 0; mi < 2; ++mi) {
    const bf16* qrow = Qp + (size_t)(qb + w * 32 + mi * 16 + lr) * LD;
    qf[mi][0] = *(const bf16x8*)(qrow + lg * 8);
    qf[mi][1] = *(const bf16x8*)(qrow + 32 + lg * 8);
  }
  asm volatile("s_waitcnt vmcnt(0)" ::: "memory");   // deterministic vmcnt counting

  // hoisted tile-invariant LDS element offsets
  int kOff0[4], kOff1[4];                 // K-frag reads, per cg
#pragma unroll
  for (int cg = 0; cg < 4; ++cg) {
    const int kr = cg * 16 + lr;
    kOff0[cg] = kr * 64 + ((lg) ^ (kr & 7)) * 8;
    kOff1[cg] = kr * 64 + ((lg + 4) ^ (kr & 7)) * 8;
  }
  int vOffLo[2][4], vOffHi[2][4];         // V b64 reads, per kc,dg
#pragma unroll
  for (int kc = 0; kc < 2; ++kc)
#pragma unroll
    for (int dg = 0; dg < 4; ++dg) {
      const int vr = dg * 16 + lr;
      vOffLo[kc][dg] = vr * 64 + ((((4 * kc + (lg >> 1)) ^ (vr & 7)) << 3) + ((lg & 1) << 2));
      vOffHi[kc][dg] = vr * 64 + ((((4 * kc + 2 + (lg >> 1)) ^ (vr & 7)) << 3) + ((lg & 1) << 2));
    }

  float m_run[2], l_part[2];                          // per-lane: q = lr (per mi)
  f32x4 o[2][4];
#pragma unroll
  for (int mi = 0; mi < 2; ++mi) {
    m_run[mi] = -3.0e38f;
    l_part[mi] = 0.0f;
#pragma unroll
    for (int dg = 0; dg < 4; ++dg) o[mi][dg] = (f32x4){0.f, 0.f, 0.f, 0.f};
  }

  auto STAGE = [&](int bi, int kt) {                 // 4 gload_lds / lane
#pragma unroll
    for (int i = 0; i < 2; ++i) {
      const int c = i * 256 + t;           // 16B chunk, 8 chunks/row
      const int r = c >> 3, slot = c & 7;
      const int ck = slot ^ (r & 7);
      gload_lds16(Kp + (size_t)(kt * 64 + r) * LD + ck * 8, &sK[bi][c * 8]);
      gload_lds16(Vt + (size_t)r * ROWS + kt * 64 + ck * 8, &sV[bi][c * 8]);
    }
  };

  const int NT = SS / 64;
  STAGE(0, 0);
  int cur = 0;

  for (int kt = 0; kt < NT; ++kt) {
    if (kt + 1 < NT) {
      STAGE(cur ^ 1, kt + 1);
      asm volatile("s_waitcnt vmcnt(4)" ::: "memory");
    } else {
      asm volatile("s_waitcnt vmcnt(0)" ::: "memory");
    }
    __builtin_amdgcn_s_barrier();

    const bf16* Kb = sK[cur];
    const bf16* Vb = sV[cur];

    // S^T = K Q^T  (s[mi][cg][r] = S[q = lr][k = cg*16 + 4*lg + r])
    f32x4 s[2][4];
    __builtin_amdgcn_s_setprio(1);
#pragma unroll
    for (int cg = 0; cg < 4; ++cg) {
      bf16x8 kf0 = *(const bf16x8*)&Kb[kOff0[cg]];
      bf16x8 kf1 = *(const bf16x8*)&Kb[kOff1[cg]];
#pragma unroll
      for (int mi = 0; mi < 2; ++mi) {
        f32x4 z = {0.f, 0.f, 0.f, 0.f};
        z = __builtin_amdgcn_mfma_f32_16x16x32_bf16(kf0, qf[mi][0], z, 0, 0, 0);
        z = __builtin_amdgcn_mfma_f32_16x16x32_bf16(kf1, qf[mi][1], z, 0, 0, 0);
        s[mi][cg] = z;
      }
    }
    __builtin_amdgcn_s_setprio(0);

    // T13 defer-max + T17 max3: lane-local max over this lane's 16 k-values.
    float pm[2];
    bool ok = true;
#pragma unroll
    for (int mi = 0; mi < 2; ++mi) {
      float a0 = max3f(s[mi][0][0], s[mi][0][1], s[mi][0][2]);
      float a1 = max3f(s[mi][0][3], s[mi][1][0], s[mi][1][1]);
      float a2 = max3f(s[mi][1][2], s[mi][1][3], s[mi][2][0]);
      float a3 = max3f(s[mi][2][1], s[mi][2][2], s[mi][2][3]);
      float a4 = max3f(s[mi][3][0], s[mi][3][1], s[mi][3][2]);
      pm[mi] = fmaxf(max3f(a0, a1, a2), max3f(a3, a4, s[mi][3][3]));
      ok = ok && (pm[mi] <= m_run[mi] + 8.f);
    }
    if (!__all(ok)) {
#pragma unroll
      for (int mi = 0; mi < 2; ++mi) {
        float m = pm[mi];
        m = fmaxf(m, __shfl_xor(m, 16));   // reduce across the 4 lg-groups
        m = fmaxf(m, __shfl_xor(m, 32));
        const float mn = fmaxf(m_run[mi], m);
        const float corr = __builtin_amdgcn_exp2f(m_run[mi] - mn);
        m_run[mi] = mn;
        l_part[mi] *= corr;
        // O rows live at q_local = 4*lg + r — fetch corr from the lane owning that q
#pragma unroll
        for (int r = 0; r < 4; ++r) {
          const float co = __shfl(corr, 20 * lg + r);
#pragma unroll
          for (int dg = 0; dg < 4; ++dg) o[mi][dg][r] *= co;
        }
      }
    }

    // P = exp2(s - m): pack DIRECTLY into PV A-fragment order (uint4 per kc):
    // pkq[mi][kc] = {cg=2kc pair01, cg=2kc pair23, cg=2kc+1 pair01, cg=2kc+1 pair23}
    uint4 pkq[2][2];
#pragma unroll
    for (int mi = 0; mi < 2; ++mi) {
#pragma unroll
      for (int kc = 0; kc < 2; ++kc) {
#pragma unroll
        for (int half = 0; half < 2; ++half) {
          const int cg = 2 * kc + half;
          float p0 = __builtin_amdgcn_exp2f(s[mi][cg][0] - m_run[mi]);
          float p1 = __builtin_amdgcn_exp2f(s[mi][cg][1] - m_run[mi]);
          float p2 = __builtin_amdgcn_exp2f(s[mi][cg][2] - m_run[mi]);
          float p3 = __builtin_amdgcn_exp2f(s[mi][cg][3] - m_run[mi]);
          l_part[mi] += (p0 + p1) + (p2 + p3);
          if (half == 0) {
            pkq[mi][kc].x = cvt_pk_bf16(p0, p1);
            pkq[mi][kc].y = cvt_pk_bf16(p2, p3);
          } else {
            pkq[mi][kc].z = cvt_pk_bf16(p0, p1);
            pkq[mi][kc].w = cvt_pk_bf16(p2, p3);
          }
        }
      }
    }

    // O += P @ V under the k-slot bijection f(lg,j)=32kc+16*(j>=4)+4lg+(j&3).
#pragma unroll
    for (int kc = 0; kc < 2; ++kc) {
      bf16x8 pf[2];
#pragma unroll
      for (int mi = 0; mi < 2; ++mi) {
        U8 a;
        a.u = pkq[mi][kc];
        pf[mi] = a.v;
      }
      __builtin_amdgcn_s_setprio(1);
#pragma unroll
      for (int dg = 0; dg < 4; ++dg) {
        uint2 lo = *(const uint2*)&Vb[vOffLo[kc][dg]];
        uint2 hi = *(const uint2*)&Vb[vOffHi[kc][dg]];
        U8 vv;
        vv.u.x = lo.x; vv.u.y = lo.y; vv.u.z = hi.x; vv.u.w = hi.y;
#pragma unroll
        for (int mi = 0; mi < 2; ++mi)
          o[mi][dg] = __builtin_amdgcn_mfma_f32_16x16x32_bf16(pf[mi], vv.v, o[mi][dg], 0, 0, 0);
      }
      __builtin_amdgcn_s_setprio(0);
    }

    asm volatile("s_waitcnt lgkmcnt(0)" ::: "memory");
    __builtin_amdgcn_sched_barrier(0);
    __builtin_amdgcn_s_barrier();
    cur ^= 1;
  }

  // final l: sum across lg-groups (q = lr), then hop to O layout (q = 4*lg + r)
#pragma unroll
  for (int mi = 0; mi < 2; ++mi) {
    float l = l_part[mi];
    l += __shfl_xor(l, 16);
    l += __shfl_xor(l, 32);
    const int orow0 = b * SS + qb + w * 32 + mi * 16 + 4 * lg;
#pragma unroll
    for (int r = 0; r < 4; ++r) {
      const float lo = __shfl(l, 20 * lg + r);
      const float inv = 1.0f / lo;
      const int row = orow0 + r;
#pragma unroll
      for (int dg = 0; dg < 4; ++dg) {
        const int col = h * 64 + dg * 16 + lr;
        ctx[(size_t)row * DM + col] = __float2bfloat16(o[mi][dg][r] * inv);
      }
    }
  }
}

// ---------------- launch ----------------
extern "C" void kernel_launch(void* const* d_in, const int* in_sizes, int n_in,
                              void* d_out, int out_size, void* d_ws, size_t ws_size,
                              hipStream_t stream) {
  const float* x   = (const float*)d_in[0];
  const float* W_q = (const float*)d_in[1];
  const float* W_k = (const float*)d_in[2];
  const float* W_v = (const float*)d_in[3];
  const float* W_o = (const float*)d_in[4];
  float* out = (float*)d_out;

  char* ws = (char*)d_ws;
  bf16* xb    = (bf16*)ws; ws += (size_t)ROWS * DM * 2;
  bf16* wqk   = (bf16*)ws; ws += (size_t)NQK * DM * 2;
  bf16* wv    = (bf16*)ws; ws += (size_t)(NG * DH) * DM * 2;
  bf16* wo    = (bf16*)ws; ws += (size_t)DM * DM * 2;
  bf16* qkbuf = (bf16*)ws; ws += (size_t)ROWS * NQK * 2;
  bf16* vtb   = (bf16*)ws; ws += (size_t)(NG * DH) * ROWS * 2;
  bf16* ctx   = (bf16*)ws; ws += (size_t)ROWS * DM * 2;

  // one fused convert: 4,718,592 float4 chunks / 256 = 18432 blocks
  cvt_all<<<18432, 256, 0, stream>>>(x, W_q, W_k, W_v, W_o, xb, wqk, wv, wo);

  // merged QK-proj (exp2 scale folded) + V-proj(transposed): 768 blocks
  gemm_qkv<<<768, 256, 0, stream>>>(xb, wqk, wv, qkbuf, vtb);
  // attention: 1024 blocks, XCD-remapped inside the kernel
  gqa_attn<<<1024, 256, 0, stream>>>(qkbuf, vtb, ctx);
  // output projection: out[4096][2048] f32 = ctx @ wo^T
  gemm_out<<<512, 256, 0, stream>>>(ctx, wo, out);
}

// Round 14
// 205.528 us; speedup vs baseline: 1.5474x; 1.0142x over previous
//
#include <hip/hip_runtime.h>
#include <hip/hip_bf16.h>
#include <stdint.h>
#include <stddef.h>

typedef __hip_bfloat16 bf16;
typedef short bf16x8 __attribute__((ext_vector_type(8)));
typedef float f32x4 __attribute__((ext_vector_type(4)));

// Problem constants
#define BB 2
#define SS 2048
#define DM 2048
#define NH 32
#define NG 8
#define DH 64
#define ROWS (BB * SS)   // 4096
#define NQK 2560         // Q cols (2048) + K cols (512)

// sqrt(0.125 * log2(e)) — applied to BOTH Q and K columns in the QK-proj GEMM,
// so S = (aQ)(aK)^T arrives pre-scaled for exp2-domain softmax.
#define ALPHA_QK 0.4246609001440095f

__device__ __forceinline__ void gload_lds16(const void* g, void* l) {
  __builtin_amdgcn_global_load_lds((const __attribute__((address_space(1))) void*)g,
                                   (__attribute__((address_space(3))) void*)l, 16, 0, 0);
}

__device__ __forceinline__ unsigned cvt_pk_bf16(float lo, float hi) {
  unsigned r;
  asm("v_cvt_pk_bf16_f32 %0, %1, %2" : "=v"(r) : "v"(lo), "v"(hi));
  return r;
}

__device__ __forceinline__ float max3f(float a, float b, float c) {
  float r;
  asm("v_max3_f32 %0, %1, %2, %3" : "=v"(r) : "v"(a), "v"(b), "v"(c));
  return r;
}

union U8 { uint4 u; bf16x8 v; };

// ---------------- fused f32 -> bf16 convert for all 5 inputs ----------------
__global__ __launch_bounds__(256) void cvt_all(const float* __restrict__ x,
                                               const float* __restrict__ wq,
                                               const float* __restrict__ wk,
                                               const float* __restrict__ wv,
                                               const float* __restrict__ wo,
                                               bf16* __restrict__ xb,
                                               bf16* __restrict__ wqkb,
                                               bf16* __restrict__ wvb,
                                               bf16* __restrict__ wob) {
  const int i = blockIdx.x * 256 + threadIdx.x;
  const float* src;
  bf16* dst;
  if (i < 2097152)       { src = x  + (size_t)i * 4;              dst = xb   + (size_t)i * 4; }
  else if (i < 3145728)  { size_t j = i - 2097152; src = wq + j * 4; dst = wqkb + j * 4; }
  else if (i < 3407872)  { size_t j = i - 3145728; src = wk + j * 4; dst = wqkb + 4194304 + j * 4; }
  else if (i < 3670016)  { size_t j = i - 3407872; src = wv + j * 4; dst = wvb  + j * 4; }
  else                   { size_t j = i - 3670016; src = wo + j * 4; dst = wob  + j * 4; }
  float4 v = *reinterpret_cast<const float4*>(src);
  bf16 t0 = __float2bfloat16(v.x), t1 = __float2bfloat16(v.y);
  bf16 t2 = __float2bfloat16(v.z), t3 = __float2bfloat16(v.w);
  ushort4 o;
  o.x = *reinterpret_cast<unsigned short*>(&t0);
  o.y = *reinterpret_cast<unsigned short*>(&t1);
  o.z = *reinterpret_cast<unsigned short*>(&t2);
  o.w = *reinterpret_cast<unsigned short*>(&t3);
  *reinterpret_cast<ushort4*>(dst) = o;
}

// ---------------- GEMM core: C[M][N] = alpha * A * B^T, 128^2 tile ----------
// 3-deep circular global_load_lds pipeline with COUNTED vmcnt (T4).
// LDS fragment offsets are tile-invariant -> hoisted before the K-loop.
__device__ __forceinline__ void store_elem(float* C, size_t i, float v) { C[i] = v; }
__device__ __forceinline__ void store_elem(bf16* C, size_t i, float v) { C[i] = __float2bfloat16(v); }

template <typename CT>
__device__ __forceinline__ void gemm_body(const bf16* __restrict__ A,
                                          const bf16* __restrict__ Bm,
                                          CT* __restrict__ C,
                                          int rowA, int rowB, int N, int K, float alpha,
                                          bf16 (*sA)[128 * 32], bf16 (*sB)[128 * 32]) {
  const int t = threadIdx.x;
  const int w = t >> 6, lane = t & 63, lg = lane >> 4, lr = lane & 15;
  const int wr = w >> 1, wc = w & 1;
  f32x4 acc[4][4] = {};

  // hoisted tile-invariant LDS element offsets
  int aOff[4], bOff[4];
#pragma unroll
  for (int mi = 0; mi < 4; ++mi) {
    const int r = wr * 64 + mi * 16 + lr;
    aOff[mi] = r * 32 + (lg ^ ((r >> 1) & 3)) * 8;
  }
#pragma unroll
  for (int ni = 0; ni < 4; ++ni) {
    const int r = wc * 64 + ni * 16 + lr;
    bOff[ni] = r * 32 + (lg ^ ((r >> 1) & 3)) * 8;
  }

  auto STAGE = [&](int bi, int k0) {               // 4 gload_lds / lane
#pragma unroll
    for (int i = 0; i < 2; ++i) {
      const int c = i * 256 + t;           // 16B chunk index, 4 chunks/row
      const int r = c >> 2, slot = c & 3;
      const int ck = slot ^ ((r >> 1) & 3);
      gload_lds16(A + (size_t)(rowA + r) * K + k0 + ck * 8, &sA[bi][c * 8]);
      gload_lds16(Bm + (size_t)(rowB + r) * K + k0 + ck * 8, &sB[bi][c * 8]);
    }
  };

  const int nt = K / 32;
  STAGE(0, 0);
  STAGE(1, 32);
  STAGE(2, 64);

  for (int i = 0; i < nt; ++i) {
    if (i <= nt - 3)      asm volatile("s_waitcnt vmcnt(8)" ::: "memory");
    else if (i == nt - 2) asm volatile("s_waitcnt vmcnt(4)" ::: "memory");
    else                  asm volatile("s_waitcnt vmcnt(0)" ::: "memory");
    __builtin_amdgcn_s_barrier();

    const int bi = i % 3;
    const bf16* Ab = sA[bi];
    const bf16* Bb = sB[bi];
    bf16x8 af[4], bfv[4];
#pragma unroll
    for (int mi = 0; mi < 4; ++mi) af[mi] = *(const bf16x8*)&Ab[aOff[mi]];
#pragma unroll
    for (int ni = 0; ni < 4; ++ni) bfv[ni] = *(const bf16x8*)&Bb[bOff[ni]];
    asm volatile("s_waitcnt lgkmcnt(0)" ::: "memory");
    __builtin_amdgcn_sched_barrier(0);
    __builtin_amdgcn_s_barrier();
    if (i + 3 < nt) STAGE(bi, (i + 3) * 32);
#pragma unroll
    for (int mi = 0; mi < 4; ++mi)
#pragma unroll
      for (int ni = 0; ni < 4; ++ni)
        acc[mi][ni] = __builtin_amdgcn_mfma_f32_16x16x32_bf16(af[mi], bfv[ni], acc[mi][ni], 0, 0, 0);
  }

#pragma unroll
  for (int mi = 0; mi < 4; ++mi)
#pragma unroll
    for (int ni = 0; ni < 4; ++ni) {
      const int row0 = rowA + wr * 64 + mi * 16 + 4 * lg;
      const int col = rowB + wc * 64 + ni * 16 + lr;
#pragma unroll
      for (int r = 0; r < 4; ++r)
        store_elem(C, (size_t)(row0 + r) * N + col, acc[mi][ni][r] * alpha);
    }
}

// Merged QK-proj + V-proj: 768 blocks (640 QK + 128 V), one XCD swizzle domain.
__global__ __launch_bounds__(256) void gemm_qkv(const bf16* __restrict__ xb,
                                                const bf16* __restrict__ wqk,
                                                const bf16* __restrict__ wv,
                                                bf16* __restrict__ qkbuf,
                                                bf16* __restrict__ vtb) {
  __shared__ __align__(16) bf16 sA[3][128 * 32];
  __shared__ __align__(16) bf16 sB[3][128 * 32];
  const int flat = blockIdx.x;                     // 768 total, %8==0
  const int swz = (flat & 7) * 96 + (flat >> 3);   // XCD-contiguous, bijective
  if (swz < 640) {
    const int rowA = (swz / 20) * 128, rowB = (swz % 20) * 128;
    gemm_body<bf16>(xb, wqk, qkbuf, rowA, rowB, NQK, DM, ALPHA_QK, sA, sB);
  } else {
    const int j = swz - 640;
    const int rowA = (j / 32) * 128, rowB = (j % 32) * 128;
    gemm_body<bf16>(wv, xb, vtb, rowA, rowB, ROWS, DM, 1.0f, sA, sB);
  }
}

// O-projection: out[4096][2048] f32 = ctx @ wo^T (512 blocks)
__global__ __launch_bounds__(256) void gemm_out(const bf16* __restrict__ ctx,
                                                const bf16* __restrict__ wo,
                                                float* __restrict__ out) {
  __shared__ __align__(16) bf16 sA[3][128 * 32];
  __shared__ __align__(16) bf16 sB[3][128 * 32];
  const int nwg = gridDim.x;                       // 512
  const int flat = blockIdx.x;
  const int swz = (flat & 7) * (nwg >> 3) + (flat >> 3);
  const int rowA = (swz / 16) * 128, rowB = (swz % 16) * 128;
  gemm_body<float>(ctx, wo, out, rowA, rowB, DM, DM, 1.0f, sA, sB);
}

// ---------------- fused GQA flash attention (m-in-MFMA-C) --------------------
// qk: [4096][2560] bf16, PRE-SCALED by sqrt(0.125*log2e) on both Q and K parts.
// vt: [512][4096] bf16 (row = g*64+d, col = b*2048+s)
// ctx: [4096][2048] bf16 out
// Block = 128 q-rows (4 waves x 32 rows), KV tile = 64, 2-deep counted-vmcnt dbuf.
// Running-max subtraction folded into the QK MFMA C-operand: C-init = -m (splat
// per lane; all 4 C-elems of a lane share its q-row = lr), so S-m comes out of
// the matrix pipe directly, and exp2 consumes the MFMA result. m tracked as
// nm = -m, starting at 0 (defer threshold bounds P by 2^8 — bf16/f32 safe).
// P stays in registers via the k-slot bijection f(lg,j)=32kc+16*(j>=4)+4lg+(j&3).
// ones-MFMA l remains SHELVED (failed 2/2 on HW); scalar l_part proven 4/4.
__global__ __launch_bounds__(256, 4) void gqa_attn(const bf16* __restrict__ qk,
                                                   const bf16* __restrict__ vt,
                                                   bf16* __restrict__ ctx) {
  const int t = threadIdx.x, w = t >> 6, lane = t & 63, lg = lane >> 4, lr = lane & 15;
  // bijective remap: flat = xcd + 8*idx  ->  wg = xcd*128 + idx
  const int flat = blockIdx.x;
  const int wg = (flat & 7) * 128 + (flat >> 3);
  const int head = wg >> 4;                 // 0..63
  const int qb = (wg & 15) * 128;           // 16 q-blocks of 128 rows
  const int b = head >> 5, h = head & 31, g = h >> 2;
  const size_t LD = NQK;
  const bf16* Qp = qk + (size_t)b * SS * LD + h * 64;
  const bf16* Kp = qk + (size_t)b * SS * LD + 2048 + g * 64;
  const bf16* Vt = vt + (size_t)(g * 64) * ROWS + b * SS;

  __shared__ __align__(16) bf16 sK[2][64 * 64];      // [key][d], slot-swizzled, dbuf
  __shared__ __align__(16) bf16 sV[2][64 * 64];      // [d][key], slot-swizzled, dbuf

  // Q B-fragments (Q^T as B-operand): lane holds q=lr, d = 8*lg+j.
  bf16x8 qf[2][2];
#pragma unroll
  for (int mi = 0; mi < 2; ++mi) {
    const bf16* qrow = Qp + (size_t)(qb + w * 32 + mi * 16 + lr) * LD;
    qf[mi][0] = *(const bf16x8*)(qrow + lg * 8);
    qf[mi][1] = *(const bf16x8*)(qrow + 32 + lg * 8);
  }
  asm volatile("s_waitcnt vmcnt(0)" ::: "memory");   // deterministic vmcnt counting

  // hoisted tile-invariant LDS element offsets
  int kOff0[4], kOff1[4];                 // K-frag reads, per cg
#pragma unroll
  for (int cg = 0; cg < 4; ++cg) {
    const int kr = cg * 16 + lr;
    kOff0[cg] = kr * 64 + ((lg) ^ (kr & 7)) * 8;
    kOff1[cg] = kr * 64 + ((lg + 4) ^ (kr & 7)) * 8;
  }
  int vOffLo[2][4], vOffHi[2][4];         // V b64 reads, per kc,dg
#pragma unroll
  for (int kc = 0; kc < 2; ++kc)
#pragma unroll
    for (int dg = 0; dg < 4; ++dg) {
      const int vr = dg * 16 + lr;
      vOffLo[kc][dg] = vr * 64 + ((((4 * kc + (lg >> 1)) ^ (vr & 7)) << 3) + ((lg & 1) << 2));
      vOffHi[kc][dg] = vr * 64 + ((((4 * kc + 2 + (lg >> 1)) ^ (vr & 7)) << 3) + ((lg & 1) << 2));
    }

  float nm[2], l_part[2];                 // nm = -running_max (q = lr); l partial
  f32x4 o[2][4];
#pragma unroll
  for (int mi = 0; mi < 2; ++mi) {
    nm[mi] = 0.0f;
    l_part[mi] = 0.0f;
#pragma unroll
    for (int dg = 0; dg < 4; ++dg) o[mi][dg] = (f32x4){0.f, 0.f, 0.f, 0.f};
  }

  auto STAGE = [&](int bi, int kt) {                 // 4 gload_lds / lane
#pragma unroll
    for (int i = 0; i < 2; ++i) {
      const int c = i * 256 + t;           // 16B chunk, 8 chunks/row
      const int r = c >> 3, slot = c & 7;
      const int ck = slot ^ (r & 7);
      gload_lds16(Kp + (size_t)(kt * 64 + r) * LD + ck * 8, &sK[bi][c * 8]);
      gload_lds16(Vt + (size_t)r * ROWS + kt * 64 + ck * 8, &sV[bi][c * 8]);
    }
  };

  const int NT = SS / 64;
  STAGE(0, 0);
  int cur = 0;

  for (int kt = 0; kt < NT; ++kt) {
    if (kt + 1 < NT) {
      STAGE(cur ^ 1, kt + 1);
      asm volatile("s_waitcnt vmcnt(4)" ::: "memory");
    } else {
      asm volatile("s_waitcnt vmcnt(0)" ::: "memory");
    }
    __builtin_amdgcn_s_barrier();

    const bf16* Kb = sK[cur];
    const bf16* Vb = sV[cur];

    // S^T = K Q^T + (-m): C-init carries the running max subtraction.
    // s[mi][cg][r] = S[q = lr][k = cg*16 + 4*lg + r] - m   (all free)
    f32x4 s[2][4];
    __builtin_amdgcn_s_setprio(1);
#pragma unroll
    for (int cg = 0; cg < 4; ++cg) {
      bf16x8 kf0 = *(const bf16x8*)&Kb[kOff0[cg]];
      bf16x8 kf1 = *(const bf16x8*)&Kb[kOff1[cg]];
#pragma unroll
      for (int mi = 0; mi < 2; ++mi) {
        f32x4 z = {nm[mi], nm[mi], nm[mi], nm[mi]};
        z = __builtin_amdgcn_mfma_f32_16x16x32_bf16(kf0, qf[mi][0], z, 0, 0, 0);
        z = __builtin_amdgcn_mfma_f32_16x16x32_bf16(kf1, qf[mi][1], z, 0, 0, 0);
        s[mi][cg] = z;
      }
    }
    __builtin_amdgcn_s_setprio(0);

    // T13 defer-max + T17 max3: pm is RELATIVE to the old max (s is shifted).
    float pm[2];
    bool ok = true;
#pragma unroll
    for (int mi = 0; mi < 2; ++mi) {
      float a0 = max3f(s[mi][0][0], s[mi][0][1], s[mi][0][2]);
      float a1 = max3f(s[mi][0][3], s[mi][1][0], s[mi][1][1]);
      float a2 = max3f(s[mi][1][2], s[mi][1][3], s[mi][2][0]);
      float a3 = max3f(s[mi][2][1], s[mi][2][2], s[mi][2][3]);
      float a4 = max3f(s[mi][3][0], s[mi][3][1], s[mi][3][2]);
      pm[mi] = fmaxf(max3f(a0, a1, a2), max3f(a3, a4, s[mi][3][3]));
      ok = ok && (pm[mi] <= 8.f);
    }
    if (!__all(ok)) {
#pragma unroll
      for (int mi = 0; mi < 2; ++mi) {
        float m = pm[mi];
        m = fmaxf(m, __shfl_xor(m, 16));   // reduce across the 4 lg-groups
        m = fmaxf(m, __shfl_xor(m, 32));
        const float d = fmaxf(m, 0.0f);    // shift of the running max
        const float corr = __builtin_amdgcn_exp2f(-d);
        nm[mi] -= d;
        l_part[mi] *= corr;
#pragma unroll
        for (int cg = 0; cg < 4; ++cg) {
          s[mi][cg][0] -= d; s[mi][cg][1] -= d;
          s[mi][cg][2] -= d; s[mi][cg][3] -= d;
        }
        // O rows live at q_local = 4*lg + r — fetch corr from the lane owning that q
#pragma unroll
        for (int r = 0; r < 4; ++r) {
          const float co = __shfl(corr, 20 * lg + r);
#pragma unroll
          for (int dg = 0; dg < 4; ++dg) o[mi][dg][r] *= co;
        }
      }
    }

    // P = exp2(s) directly (s already max-shifted); pack into PV A-frag order.
    uint4 pkq[2][2];
#pragma unroll
    for (int mi = 0; mi < 2; ++mi) {
#pragma unroll
      for (int kc = 0; kc < 2; ++kc) {
#pragma unroll
        for (int half = 0; half < 2; ++half) {
          const int cg = 2 * kc + half;
          float p0 = __builtin_amdgcn_exp2f(s[mi][cg][0]);
          float p1 = __builtin_amdgcn_exp2f(s[mi][cg][1]);
          float p2 = __builtin_amdgcn_exp2f(s[mi][cg][2]);
          float p3 = __builtin_amdgcn_exp2f(s[mi][cg][3]);
          l_part[mi] += (p0 + p1) + (p2 + p3);
          if (half == 0) {
            pkq[mi][kc].x = cvt_pk_bf16(p0, p1);
            pkq[mi][kc].y = cvt_pk_bf16(p2, p3);
          } else {
            pkq[mi][kc].z = cvt_pk_bf16(p0, p1);
            pkq[mi][kc].w = cvt_pk_bf16(p2, p3);
          }
        }
      }
    }

    // O += P @ V under the k-slot bijection f(lg,j)=32kc+16*(j>=4)+4lg+(j&3).
#pragma unroll
    for (int kc = 0; kc < 2; ++kc) {
      bf16x8 pf[2];
#pragma unroll
      for (int mi = 0; mi < 2; ++mi) {
        U8 a;
        a.u = pkq[mi][kc];
        pf[mi] = a.v;
      }
      __builtin_amdgcn_s_setprio(1);
#pragma unroll
      for (int dg = 0; dg < 4; ++dg) {
        uint2 lo = *(const uint2*)&Vb[vOffLo[kc][dg]];
        uint2 hi = *(const uint2*)&Vb[vOffHi[kc][dg]];
        U8 vv;
        vv.u.x = lo.x; vv.u.y = lo.y; vv.u.z = hi.x; vv.u.w = hi.y;
#pragma unroll
        for (int mi = 0; mi < 2; ++mi)
          o[mi][dg] = __builtin_amdgcn_mfma_f32_16x16x32_bf16(pf[mi], vv.v, o[mi][dg], 0, 0, 0);
      }
      __builtin_amdgcn_s_setprio(0);
    }

    asm volatile("s_waitcnt lgkmcnt(0)" ::: "memory");
    __builtin_amdgcn_sched_barrier(0);
    __builtin_amdgcn_s_barrier();
    cur ^= 1;
  }

  // final l: sum across lg-groups (q = lr), then hop to O layout (q = 4*lg + r)
#pragma unroll
  for (int mi = 0; mi < 2; ++mi) {
    float l = l_part[mi];
    l += __shfl_xor(l, 16);
    l += __shfl_xor(l, 32);
    const int orow0 = b * SS + qb + w * 32 + mi * 16 + 4 * lg;
#pragma unroll
    for (int r = 0; r < 4; ++r) {
      const float lo = __shfl(l, 20 * lg + r);
      const float inv = 1.0f / lo;
      const int row = orow0 + r;
#pragma unroll
      for (int dg = 0; dg < 4; ++dg) {
        const int col = h * 64 + dg * 16 + lr;
        ctx[(size_t)row * DM + col] = __float2bfloat16(o[mi][dg][r] * inv);
      }
    }
  }
}

// ---------------- launch ----------------
extern "C" void kernel_launch(void* const* d_in, const int* in_sizes, int n_in,
                              void* d_out, int out_size, void* d_ws, size_t ws_size,
                              hipStream_t stream) {
  const float* x   = (const float*)d_in[0];
  const float* W_q = (const float*)d_in[1];
  const float* W_k = (const float*)d_in[2];
  const float* W_v = (const float*)d_in[3];
  const float* W_o = (const float*)d_in[4];
  float* out = (float*)d_out;

  char* ws = (char*)d_ws;
  bf16* xb    = (bf16*)ws; ws += (size_t)ROWS * DM * 2;
  bf16* wqk   = (bf16*)ws; ws += (size_t)NQK * DM * 2;
  bf16* wv    = (bf16*)ws; ws += (size_t)(NG * DH) * DM * 2;
  bf16* wo    = (bf16*)ws; ws += (size_t)DM * DM * 2;
  bf16* qkbuf = (bf16*)ws; ws += (size_t)ROWS * NQK * 2;
  bf16* vtb   = (bf16*)ws; ws += (size_t)(NG * DH) * ROWS * 2;
  bf16* ctx   = (bf16*)ws; ws += (size_t)ROWS * DM * 2;

  // one fused convert: 4,718,592 float4 chunks / 256 = 18432 blocks
  cvt_all<<<18432, 256, 0, stream>>>(x, W_q, W_k, W_v, W_o, xb, wqk, wv, wo);

  // merged QK-proj (exp2 scale folded) + V-proj(transposed): 768 blocks
  gemm_qkv<<<768, 256, 0, stream>>>(xb, wqk, wv, qkbuf, vtb);
  // attention: 1024 blocks, XCD-remapped inside the kernel
  gqa_attn<<<1024, 256, 0, stream>>>(qkbuf, vtb, ctx);
  // output projection: out[4096][2048] f32 = ctx @ wo^T
  gemm_out<<<512, 256, 0, stream>>>(ctx, wo, out);
}